// Round 17
// baseline (291.063 us; speedup 1.0000x reference)
//
#include <hip/hip_runtime.h>
#include <hip/hip_bf16.h>
#include <math.h>

typedef __attribute__((ext_vector_type(8))) short s16x8;
typedef __attribute__((ext_vector_type(4))) short s16x4;
typedef __attribute__((ext_vector_type(4))) float f32x4;
typedef __attribute__((ext_vector_type(8))) __bf16 bf16x8;

#define MFMA16(a, b, c) __builtin_amdgcn_mfma_f32_16x16x32_bf16( \
    __builtin_bit_cast(bf16x8, (a)), __builtin_bit_cast(bf16x8, (b)), (c), 0, 0, 0)

__device__ __forceinline__ short f2b(float f) {
    __bf16 h = (__bf16)f;
    return __builtin_bit_cast(short, h);
}
__device__ __forceinline__ float b2f(short b) {
    union { unsigned u; float f; } x;
    x.u = ((unsigned)(unsigned short)b) << 16;
    return x.f;
}

__device__ __forceinline__ void gload16(const void* g, void* l) {
    __builtin_amdgcn_global_load_lds(
        (const __attribute__((address_space(1))) unsigned int*)g,
        (__attribute__((address_space(3))) unsigned int*)l, 16, 0, 0);
}

// ---------------- fp32 -> bf16 convert (hidden states) ----------------
__global__ void k_f32_to_bf16(const float* __restrict__ in, short* __restrict__ out, long n) {
    long i = ((long)blockIdx.x * blockDim.x + threadIdx.x) * 4;
    long stride = (long)gridDim.x * blockDim.x * 4;
    for (; i < n; i += stride) {
        float4 v = *(const float4*)(in + i);
        s16x4 o = { f2b(v.x), f2b(v.y), f2b(v.z), f2b(v.w) };
        *(s16x4*)(out + i) = o;
    }
}

// ---------------- fused 4-weight convert ----------------
__global__ void k_wconv4(const float* __restrict__ w0, const float* __restrict__ w1,
                         const float* __restrict__ w2, const float* __restrict__ w3,
                         short* __restrict__ out, long n) {
    int wsel = blockIdx.y;
    const float* src = (wsel == 0) ? w0 : (wsel == 1) ? w1 : (wsel == 2) ? w2 : w3;
    short* dst = out + (long)wsel * n;
    long i = ((long)blockIdx.x * blockDim.x + threadIdx.x) * 4;
    if (i >= n) return;
    float4 v = *(const float4*)(src + i);
    s16x4 o = { f2b(v.x), f2b(v.y), f2b(v.z), f2b(v.w) };
    *(s16x4*)(dst + i) = o;
}

// ---------------- raw size with 0-padding ----------------
__global__ void k_sizepad(const float* __restrict__ size, float* __restrict__ out,
                          int B, int T, int SP) {
    int i = blockIdx.x * blockDim.x + threadIdx.x;
    if (i >= B * SP) return;
    int b = i / SP, s = i % SP;
    out[i] = (s < T) ? size[b * T + s] : 0.f;
}

// ======== QKV core: 128x128 4-wave, BK=64, single-buffer 32KB LDS (round-14 optimum) ========
template<bool ROUTE>
__global__ __launch_bounds__(256) void k_gemm4(
    const short* __restrict__ A, const short* __restrict__ Bw,
    const float* __restrict__ bb0, const float* __restrict__ bb1, const float* __restrict__ bb2,
    short* __restrict__ o0, short* __restrict__ o1, short* __restrict__ o2,
    float* __restrict__ Cf, int M, int N, int K, int Ntiles, float alpha0) {

    __shared__ short As[128 * 64];
    __shared__ short Bs[128 * 64];

    int nwg = gridDim.x, orig = blockIdx.x;
    int qq = nwg >> 3, rr = nwg & 7;
    int xcd = orig & 7, pos = orig >> 3;
    int wg = (xcd < rr ? xcd * (qq + 1) : rr * (qq + 1) + (xcd - rr) * qq) + pos;
    int bx = wg % Ntiles, by = wg / Ntiles;
    int row0 = by * 128, col0 = bx * 128;

    int tid = threadIdx.x;
    int lane = tid & 63, wave = tid >> 6;
    int wr = wave >> 1, wc = wave & 1;
    int lr = lane & 15, lg = lane >> 4;

    f32x4 acc[4][4];
    #pragma unroll
    for (int i = 0; i < 4; i++)
        #pragma unroll
        for (int j = 0; j < 4; j++)
            #pragma unroll
            for (int q = 0; q < 4; q++) acc[i][j][q] = 0.f;

    for (int k0 = 0; k0 < K; k0 += 64) {
        __syncthreads();
        #pragma unroll
        for (int i = 0; i < 4; ++i) {
            int cw = i * 256 + wave * 64;
            int c = cw + lane;
            int r = c >> 3;
            int cby = ((c & 7) * 16) ^ ((r & 7) << 4);
            int ra = row0 + r; ra = ra < M ? ra : M - 1;
            gload16((const char*)(A + (long)ra * K + k0) + cby, &As[cw * 8]);
            int rb = col0 + r; rb = rb < N ? rb : N - 1;
            gload16((const char*)(Bw + (long)rb * K + k0) + cby, &Bs[cw * 8]);
        }
        __syncthreads();
        #pragma unroll
        for (int ks = 0; ks < 2; ++ks) {
            s16x8 af[4], bfr[4];
            #pragma unroll
            for (int i = 0; i < 4; ++i) {
                int r = wr * 64 + i * 16 + lr;
                af[i] = *(const s16x8*)((const char*)As + r * 128 +
                        (((ks << 6) + (lg << 4)) ^ ((r & 7) << 4)));
            }
            #pragma unroll
            for (int j = 0; j < 4; ++j) {
                int r = wc * 64 + j * 16 + lr;
                bfr[j] = *(const s16x8*)((const char*)Bs + r * 128 +
                         (((ks << 6) + (lg << 4)) ^ ((r & 7) << 4)));
            }
            #pragma unroll
            for (int i = 0; i < 4; ++i)
                #pragma unroll
                for (int j = 0; j < 4; ++j)
                    acc[i][j] = MFMA16(af[i], bfr[j], acc[i][j]);
        }
    }

    #pragma unroll
    for (int i = 0; i < 4; i++) {
        int grow0 = row0 + wr * 64 + i * 16 + lg * 4;
        #pragma unroll
        for (int j = 0; j < 4; j++) {
            int gc = col0 + wc * 64 + j * 16 + lr;
            if (gc >= N) continue;
            if (ROUTE) {
                int which = gc >> 10, lc = gc & 1023;
                float bias = (which == 0 ? bb0 : which == 1 ? bb1 : bb2)[lc];
                float alpha = (which == 0) ? alpha0 : 1.0f;
                short* op = (which == 0 ? o0 : which == 1 ? o1 : o2);
                #pragma unroll
                for (int q = 0; q < 4; ++q) {
                    int r2 = grow0 + q;
                    if (r2 < M) op[(long)r2 * 1024 + lc] = f2b((acc[i][j][q] + bias) * alpha);
                }
            } else {
                float bias = bb0[gc];
                #pragma unroll
                for (int q = 0; q < 4; ++q) {
                    int r2 = grow0 + q;
                    if (r2 < M) Cf[(long)r2 * N + gc] = acc[i][j][q] + bias;
                }
            }
        }
    }
}

// ======== latency-hiding core: BK=32, 2-deep dbuf in 32KB LDS (round-16, for att/proj) ====
__device__ __forceinline__ void core32(
    const short* __restrict__ A, const short* __restrict__ Bw,
    int M, int N, int K, int row0, int col0,
    short* AS, short* BS,
    f32x4 acc[4][4]) {
    int tid = threadIdx.x;
    int lane = tid & 63, wave = tid >> 6;
    int wr = wave >> 1, wc = wave & 1;
    int lr = lane & 15, lg = lane >> 4;

    const char* ga[2]; const char* gb[2]; int ldo[2];
    #pragma unroll
    for (int j = 0; j < 2; ++j) {
        int ch = j * 256 + wave * 64 + lane;
        int r = ch >> 2, slot = ch & 3;
        int cby = (slot << 4) ^ (((r >> 1) & 3) << 4);
        int ra = row0 + r; ra = ra < M ? ra : M - 1;
        int rb = col0 + r; rb = rb < N ? rb : N - 1;
        ga[j] = (const char*)(A + (long)ra * K) + cby;
        gb[j] = (const char*)(Bw + (long)rb * K) + cby;
        ldo[j] = ch * 8;
    }
    #pragma unroll
    for (int i = 0; i < 4; i++)
        #pragma unroll
        for (int j = 0; j < 4; j++)
            #pragma unroll
            for (int q = 0; q < 4; q++) acc[i][j][q] = 0.f;

    #pragma unroll
    for (int j = 0; j < 2; ++j) {
        gload16(ga[j], AS + ldo[j]);
        gload16(gb[j], BS + ldo[j]);
        ga[j] += 64; gb[j] += 64;
    }

    int nt = K >> 5;
    for (int t = 0; t < nt; ++t) {
        int cur = t & 1;
        asm volatile("s_waitcnt vmcnt(0)" ::: "memory");
        __builtin_amdgcn_s_barrier();
        if (t + 1 < nt) {
            short* Ad = AS + (cur ^ 1) * 4096;
            short* Bd = BS + (cur ^ 1) * 4096;
            #pragma unroll
            for (int j = 0; j < 2; ++j) {
                gload16(ga[j], Ad + ldo[j]);
                gload16(gb[j], Bd + ldo[j]);
                ga[j] += 64; gb[j] += 64;
            }
        }
        const short* Ab2 = AS + cur * 4096;
        const short* Bb2 = BS + cur * 4096;
        s16x8 af[4], bfr[4];
        #pragma unroll
        for (int i = 0; i < 4; ++i) {
            int r = wr * 64 + i * 16 + lr;
            af[i] = *(const s16x8*)((const char*)Ab2 + r * 64 +
                    ((lg << 4) ^ (((r >> 1) & 3) << 4)));
        }
        #pragma unroll
        for (int j = 0; j < 4; ++j) {
            int r = wc * 64 + j * 16 + lr;
            bfr[j] = *(const s16x8*)((const char*)Bb2 + r * 64 +
                     ((lg << 4) ^ (((r >> 1) & 3) << 4)));
        }
        __builtin_amdgcn_s_setprio(1);
        #pragma unroll
        for (int i = 0; i < 4; ++i)
            #pragma unroll
            for (int j = 0; j < 4; ++j)
                acc[i][j] = MFMA16(af[i], bfr[j], acc[i][j]);
        __builtin_amdgcn_s_setprio(0);
    }
}

// proj on core32 (fp32 epilogue + bias)
__global__ __launch_bounds__(256) void k_proj32(
    const short* __restrict__ A, const short* __restrict__ Bw,
    const float* __restrict__ bias, float* __restrict__ Cf,
    int M, int N, int K, int Ntiles) {
    __shared__ short AS[2][128 * 32];
    __shared__ short BS[2][128 * 32];

    int nwg = gridDim.x, orig = blockIdx.x;
    int qq = nwg >> 3, rr = nwg & 7;
    int xcd = orig & 7, pos = orig >> 3;
    int wg = (xcd < rr ? xcd * (qq + 1) : rr * (qq + 1) + (xcd - rr) * qq) + pos;
    int bx = wg % Ntiles, by = wg / Ntiles;
    int row0 = by * 128, col0 = bx * 128;

    int tid = threadIdx.x;
    int lane = tid & 63, wave = tid >> 6;
    int wr = wave >> 1, wc = wave & 1;
    int lr = lane & 15, lg = lane >> 4;

    f32x4 acc[4][4];
    core32(A, Bw, M, N, K, row0, col0, &AS[0][0], &BS[0][0], acc);

    #pragma unroll
    for (int i = 0; i < 4; i++) {
        int grow0 = row0 + wr * 64 + i * 16 + lg * 4;
        #pragma unroll
        for (int j = 0; j < 4; j++) {
            int gc = col0 + wc * 64 + j * 16 + lr;
            if (gc >= N) continue;
            float bv = bias[gc];
            #pragma unroll
            for (int q = 0; q < 4; ++q) {
                int r2 = grow0 + q;
                if (r2 < M) Cf[(long)r2 * N + gc] = acc[i][j][q] + bv;
            }
        }
    }
}

// ---------------- att partials: core32, fp32 epilogue ----------------
__global__ __launch_bounds__(256) void k_att(
    const short* __restrict__ q, const short* __restrict__ k,
    float* __restrict__ attp, int T, int E) {
    __shared__ short AS[2][128 * 32];
    __shared__ short BS[2][128 * 32];
    int z = blockIdx.z;
    const short* Ab = q + (long)z * T * E;
    const short* Bb = k + (long)z * T * E;
    float* Cf = attp + (long)z * T * T;
    int row0 = blockIdx.y * 128, col0 = blockIdx.x * 128;

    int tid = threadIdx.x;
    int lane = tid & 63, wave = tid >> 6;
    int wr = wave >> 1, wc = wave & 1;
    int lr = lane & 15, lg = lane >> 4;

    f32x4 acc[4][4];
    core32(Ab, Bb, T, T, E, row0, col0, &AS[0][0], &BS[0][0], acc);

    #pragma unroll
    for (int i = 0; i < 4; i++) {
        int rbase = row0 + wr * 64 + i * 16 + lg * 4;
        #pragma unroll
        for (int j = 0; j < 4; j++) {
            int c = col0 + wc * 64 + j * 16 + lr;
            if (c >= T) continue;
            #pragma unroll
            for (int q2 = 0; q2 < 4; q2++) {
                int r = rbase + q2;
                if (r >= T) continue;
                Cf[(long)r * T + c] = acc[i][j][q2];
            }
        }
    }
}

// ---------------- mean over heads of K ----------------
__global__ void k_mean_keys8(const short* __restrict__ Kb, float* __restrict__ out, int BT) {
    int i = blockIdx.x * blockDim.x + threadIdx.x;
    if (i >= BT * 8) return;
    int bt = i >> 3, d0 = (i & 7) * 8;
    const short* p = Kb + (long)bt * 1024 + d0;
    float s[8] = {0.f, 0.f, 0.f, 0.f, 0.f, 0.f, 0.f, 0.f};
    #pragma unroll
    for (int h = 0; h < 16; ++h) {
        s16x8 v = *(const s16x8*)(p + h * 64);
        #pragma unroll
        for (int j = 0; j < 8; ++j) s[j] += b2f(v[j]);
    }
    float4 o0 = {s[0] * 0.0625f, s[1] * 0.0625f, s[2] * 0.0625f, s[3] * 0.0625f};
    float4 o1 = {s[4] * 0.0625f, s[5] * 0.0625f, s[6] * 0.0625f, s[7] * 0.0625f};
    *(float4*)(out + (long)bt * 64 + d0) = o0;
    *(float4*)(out + (long)bt * 64 + d0 + 4) = o1;
}

// ---------------- reduce att_score partials over batch ----------------
__global__ void k_att_reduce(const float* __restrict__ part, float* __restrict__ out,
                             int n, int nb, long stride) {
    int i = blockIdx.x * blockDim.x + threadIdx.x;
    if (i >= n) return;
    float s = 0.f;
    for (int b = 0; b < nb; ++b) s += part[(long)b * stride + i];
    out[i] = s * 0.002707606174062286f;  // ln(2)/256 compensates log2e folded into q
}

// ---------------- V transpose + size pre-scale ----------------
__global__ __launch_bounds__(256) void k_vtrans(const short* __restrict__ v, short* __restrict__ vt,
                                                const float* __restrict__ szp,
                                                int B, int T, int H, int TP, int SP) {
    int b = blockIdx.z, h = blockIdx.y, t0 = blockIdx.x * 64;
    __shared__ short Vs[64][68];
    __shared__ float Szs[64];
    int tid = threadIdx.x;
    if (tid < 64) Szs[tid] = szp[b * SP + t0 + tid];
    for (int c = tid; c < 512; c += 256) {
        int r = c >> 3, m = c & 7;
        s16x8 val = {0,0,0,0,0,0,0,0};
        if (t0 + r < T) val = *(const s16x8*)(v + ((long)(b * T + t0 + r)) * (H * 64) + h * 64 + m * 8);
        *(s16x8*)&Vs[r][m * 8] = val;
    }
    __syncthreads();
    for (int c = tid; c < 512; c += 256) {
        int d = c >> 3, mw = c & 7;
        s16x8 o;
        #pragma unroll
        for (int j = 0; j < 8; j++) o[j] = f2b(b2f(Vs[mw * 8 + j][d]) * Szs[mw * 8 + j]);
        *(s16x8*)(vt + ((long)((b * H + h) * 64 + d)) * TP + t0 + mw * 8) = o;
    }
}

// ---------------- flash attention v5: size folded into V'; lsum via 65th-column MFMA ----------------
__global__ __launch_bounds__(256) void k_flash(
    const short* __restrict__ Q, const short* __restrict__ Kb, const short* __restrict__ VT,
    const float* __restrict__ szp, short* __restrict__ Ctx,
    int B, int T, int E, int H, int SP, int TP, int NTQ) {
    int nwg = gridDim.x;
    int cpx = nwg >> 3;
    int wg = (blockIdx.x & 7) * cpx + (blockIdx.x >> 3);
    int tq = wg % NTQ, h = (wg / NTQ) % H, b = wg / (NTQ * H);
    int t0 = tq * 128;

    __shared__ short Ks[64][68];
    __shared__ short Vt[80][68];
    __shared__ short Ps[4][32][68];
    int tid = threadIdx.x, wid = tid >> 6, lane = tid & 63;
    int lr = lane & 15, lg = lane >> 4;

    for (int c = tid; c < 15 * 68; c += 256) Vt[65 + c / 68][c % 68] = 0;

    s16x8 aqf[2][2];
    #pragma unroll
    for (int i = 0; i < 2; ++i) {
        int t = t0 + wid * 32 + i * 16 + lr; t = t < T ? t : T - 1;
        #pragma unroll
        for (int ks = 0; ks < 2; ++ks)
            aqf[i][ks] = *(const s16x8*)(Q + ((long)b * T + t) * E + h * 64 + ks * 32 + lg * 8);
    }

    const short* kb  = Kb + (long)b * T * E + h * 64;
    const short* vtb = VT + ((long)(b * H + h)) * 64 * TP;

    int c0 = tid, c1 = tid + 256;
    int r0 = c0 >> 3, m0 = c0 & 7, r1 = c1 >> 3, m1 = c1 & 7;
    s16x8 kreg0, kreg1, vreg0, vreg1;
    float szreg = 0.f;

    {
        int s = r0; s = s < T ? s : T - 1;
        kreg0 = *(const s16x8*)(kb + (long)s * E + m0 * 8);
        s = r1; s = s < T ? s : T - 1;
        kreg1 = *(const s16x8*)(kb + (long)s * E + m1 * 8);
        vreg0 = *(const s16x8*)(vtb + (long)r0 * TP + 0 + m0 * 8);
        vreg1 = *(const s16x8*)(vtb + (long)r1 * TP + 0 + m1 * 8);
        if (tid < 64) szreg = szp[b * SP + 0 + tid];
    }

    float mreg[2][4];
    f32x4 o[2][5];
    #pragma unroll
    for (int i = 0; i < 2; i++)
        #pragma unroll
        for (int q = 0; q < 4; q++) mreg[i][q] = -INFINITY;
    #pragma unroll
    for (int i = 0; i < 2; i++)
        #pragma unroll
        for (int jd = 0; jd < 5; jd++)
            #pragma unroll
            for (int q = 0; q < 4; q++) o[i][jd][q] = 0.f;

    for (int s0 = 0; s0 < T; s0 += 64) {
        *(s16x8*)&Ks[r0][m0 * 8] = kreg0;
        *(s16x8*)&Ks[r1][m1 * 8] = kreg1;
        *(s16x8*)&Vt[r0][m0 * 8] = vreg0;
        *(s16x8*)&Vt[r1][m1 * 8] = vreg1;
        if (tid < 64) Vt[64][tid] = f2b(szreg);
        __syncthreads();

        if (s0 + 64 < T) {
            int sn = s0 + 64;
            int s = sn + r0; s = s < T ? s : T - 1;
            kreg0 = *(const s16x8*)(kb + (long)s * E + m0 * 8);
            s = sn + r1; s = s < T ? s : T - 1;
            kreg1 = *(const s16x8*)(kb + (long)s * E + m1 * 8);
            vreg0 = *(const s16x8*)(vtb + (long)r0 * TP + sn + m0 * 8);
            vreg1 = *(const s16x8*)(vtb + (long)r1 * TP + sn + m1 * 8);
            if (tid < 64) szreg = szp[b * SP + sn + tid];
        }

        s16x8 kf[2][4];
        #pragma unroll
        for (int ks = 0; ks < 2; ++ks)
            #pragma unroll
            for (int j = 0; j < 4; ++j)
                kf[ks][j] = *(const s16x8*)&Ks[j * 16 + lr][ks * 32 + lg * 8];

        #pragma unroll
        for (int i = 0; i < 2; ++i) {
            f32x4 sf[4];
            #pragma unroll
            for (int j = 0; j < 4; j++)
                #pragma unroll
                for (int q = 0; q < 4; q++) sf[j][q] = 0.f;
            __builtin_amdgcn_s_setprio(1);
            #pragma unroll
            for (int ks = 0; ks < 2; ++ks)
                #pragma unroll
                for (int j = 0; j < 4; j++) sf[j] = MFMA16(aqf[i][ks], kf[ks][j], sf[j]);
            __builtin_amdgcn_s_setprio(0);

            float tmax[4];
            #pragma unroll
            for (int q = 0; q < 4; q++)
                tmax[q] = fmaxf(fmaxf(sf[0][q], sf[1][q]), fmaxf(sf[2][q], sf[3][q]));
            int ok = 1;
            #pragma unroll
            for (int q = 0; q < 4; q++) ok &= (tmax[q] <= mreg[i][q] + 11.0f) ? 1 : 0;
            if (!__all(ok)) {
                #pragma unroll
                for (int q = 0; q < 4; q++) {
                    #pragma unroll
                    for (int msk = 1; msk < 16; msk <<= 1)
                        tmax[q] = fmaxf(tmax[q], __shfl_xor(tmax[q], msk));
                    float mn = fmaxf(mreg[i][q], tmax[q]);
                    float al = exp2f(mreg[i][q] - mn);
                    mreg[i][q] = mn;
                    #pragma unroll
                    for (int jd = 0; jd < 5; jd++) o[i][jd][q] *= al;
                }
            }
            #pragma unroll
            for (int j = 0; j < 4; j++)
                #pragma unroll
                for (int q = 0; q < 4; q++)
                    Ps[wid][i * 16 + lg * 4 + q][j * 16 + lr] = f2b(exp2f(sf[j][q] - mreg[i][q]));

            __builtin_amdgcn_s_setprio(1);
            #pragma unroll
            for (int ks = 0; ks < 2; ++ks) {
                s16x8 ap = *(const s16x8*)&Ps[wid][i * 16 + lr][ks * 32 + lg * 8];
                #pragma unroll
                for (int jd = 0; jd < 5; jd++) {
                    s16x8 bv = *(const s16x8*)&Vt[jd * 16 + lr][ks * 32 + lg * 8];
                    o[i][jd] = MFMA16(ap, bv, o[i][jd]);
                }
            }
            __builtin_amdgcn_s_setprio(0);
        }
        __syncthreads();
    }

    short* cb = Ctx + ((long)b * T + t0) * E + h * 64;
    #pragma unroll
    for (int i = 0; i < 2; i++)
        #pragma unroll
        for (int q = 0; q < 4; q++) {
            float s = __shfl(o[i][4][q], lane & 48);
            int t = wid * 32 + i * 16 + lg * 4 + q;
            if (t0 + t >= T) continue;
            float inv = 1.f / s;
            #pragma unroll
            for (int jd = 0; jd < 4; jd++)
                cb[(long)t * E + jd * 16 + lr] = f2b(o[i][jd][q] * inv);
        }
}

extern "C" void kernel_launch(void* const* d_in, const int* in_sizes, int n_in,
                              void* d_out, int out_size, void* d_ws, size_t ws_size,
                              hipStream_t stream) {
    (void)in_sizes; (void)n_in; (void)out_size; (void)ws_size;
    const int B = 16, T = 577, E = 1024, H = 16;
    const int SP = 640, TP = 640;
    const float* hs   = (const float*)d_in[0];
    const float* size = (const float*)d_in[1];
    const float* wq   = (const float*)d_in[2];
    const float* bq   = (const float*)d_in[3];
    const float* wk   = (const float*)d_in[4];
    const float* bk   = (const float*)d_in[5];
    const float* wv   = (const float*)d_in[6];
    const float* bv   = (const float*)d_in[7];
    const float* wo   = (const float*)d_in[8];
    const float* bo   = (const float*)d_in[9];

    float* out_attn = (float*)d_out;                  // B*T*E
    float* out_mk   = out_attn + (long)B * T * E;     // B*T*D
    float* out_as   = out_mk + (long)B * T * 64;      // T*T

    long nBTE = (long)B * T * E;
    long nEE  = (long)E * E;
    char* ws = (char*)d_ws;
    short* hs_b  = (short*)ws; ws += nBTE * 2;
    short* wq_b  = (short*)ws; ws += nEE * 2;   // wq|wk|wv|wo contiguous
    short* wk_b  = (short*)ws; ws += nEE * 2;
    short* wv_b  = (short*)ws; ws += nEE * 2;
    short* wo_b  = (short*)ws; ws += nEE * 2;
    short* q_b   = (short*)ws; ws += nBTE * 2;
    short* k_b   = (short*)ws; ws += nBTE * 2;
    short* v_b   = (short*)ws; ws += nBTE * 2;
    short* ctx_b = (short*)ws; ws += nBTE * 2;
    float* szpad = (float*)ws; ws += (long)B * SP * 4;
    float* att_p = (float*)ws; ws += (long)B * T * T * 4;
    short* vt = (short*)att_p;   // aliases att_p, written after reduce consumed it

    k_f32_to_bf16<<<2048, 256, 0, stream>>>(hs, hs_b, nBTE);
    {
        dim3 gw((nEE / 4 + 255) / 256, 4);
        k_wconv4<<<gw, 256, 0, stream>>>(wq, wk, wv, wo, wq_b, nEE);
    }
    k_sizepad<<<(B * SP + 255) / 256, 256, 0, stream>>>(size, szpad, B, T, SP);

    int M = B * T;  // 9232
    // fused QKV: BK64 single-buffer core (best measured for this dispatch)
    {
        int Mtiles = (M + 127) / 128, Ntiles = 3072 / 128;   // 73 x 24 = 1752 blocks
        k_gemm4<true><<<Mtiles * Ntiles, 256, 0, stream>>>(
            hs_b, wq_b, bq, bk, bv, q_b, k_b, v_b, nullptr, M, 3072, E, Ntiles,
            0.18033688011112042f);  // 0.125 * log2(e)
    }

    dim3 g_att((T + 127) / 128, (T + 127) / 128, B);
    k_att<<<g_att, dim3(256), 0, stream>>>(q_b, k_b, att_p, T, E);
    k_att_reduce<<<((T * T) + 255) / 256, 256, 0, stream>>>(att_p, out_as, T * T, B, (long)T * T);

    dim3 g_vt((T + 63) / 64, H, B);
    k_vtrans<<<g_vt, dim3(256), 0, stream>>>(v_b, vt, szpad, B, T, H, TP, SP);

    k_mean_keys8<<<((B * T * 8) + 255) / 256, 256, 0, stream>>>(k_b, out_mk, B * T);

    const int NTQ = (T + 127) / 128;
    int nfl = NTQ * H * B;
    k_flash<<<nfl, dim3(256), 0, stream>>>(q_b, k_b, vt, szpad, ctx_b, B, T, E, H, SP, TP, NTQ);

    // output projection: core32 dbuf (latency-hiding pays on the short grid)
    {
        int Mtiles = (M + 127) / 128, Ntiles = 1024 / 128;   // 73 x 8 = 584 blocks
        k_proj32<<<Mtiles * Ntiles, 256, 0, stream>>>(
            ctx_b, wo_b, bo, out_attn, M, 1024, E, Ntiles);
    }
}

// Round 18
// 289.801 us; speedup vs baseline: 1.0044x; 1.0044x over previous
//
#include <hip/hip_runtime.h>
#include <hip/hip_bf16.h>
#include <math.h>

typedef __attribute__((ext_vector_type(8))) short s16x8;
typedef __attribute__((ext_vector_type(4))) short s16x4;
typedef __attribute__((ext_vector_type(4))) float f32x4;
typedef __attribute__((ext_vector_type(8))) __bf16 bf16x8;

#define MFMA16(a, b, c) __builtin_amdgcn_mfma_f32_16x16x32_bf16( \
    __builtin_bit_cast(bf16x8, (a)), __builtin_bit_cast(bf16x8, (b)), (c), 0, 0, 0)

__device__ __forceinline__ short f2b(float f) {
    __bf16 h = (__bf16)f;
    return __builtin_bit_cast(short, h);
}
__device__ __forceinline__ float b2f(short b) {
    union { unsigned u; float f; } x;
    x.u = ((unsigned)(unsigned short)b) << 16;
    return x.f;
}

__device__ __forceinline__ void gload16(const void* g, void* l) {
    __builtin_amdgcn_global_load_lds(
        (const __attribute__((address_space(1))) unsigned int*)g,
        (__attribute__((address_space(3))) unsigned int*)l, 16, 0, 0);
}

// ---------------- fp32 -> bf16 convert (hidden states) ----------------
__global__ void k_f32_to_bf16(const float* __restrict__ in, short* __restrict__ out, long n) {
    long i = ((long)blockIdx.x * blockDim.x + threadIdx.x) * 4;
    long stride = (long)gridDim.x * blockDim.x * 4;
    for (; i < n; i += stride) {
        float4 v = *(const float4*)(in + i);
        s16x4 o = { f2b(v.x), f2b(v.y), f2b(v.z), f2b(v.w) };
        *(s16x4*)(out + i) = o;
    }
}

// ---------------- fused 4-weight convert ----------------
__global__ void k_wconv4(const float* __restrict__ w0, const float* __restrict__ w1,
                         const float* __restrict__ w2, const float* __restrict__ w3,
                         short* __restrict__ out, long n) {
    int wsel = blockIdx.y;
    const float* src = (wsel == 0) ? w0 : (wsel == 1) ? w1 : (wsel == 2) ? w2 : w3;
    short* dst = out + (long)wsel * n;
    long i = ((long)blockIdx.x * blockDim.x + threadIdx.x) * 4;
    if (i >= n) return;
    float4 v = *(const float4*)(src + i);
    s16x4 o = { f2b(v.x), f2b(v.y), f2b(v.z), f2b(v.w) };
    *(s16x4*)(dst + i) = o;
}

// ---------------- raw size with 0-padding ----------------
__global__ void k_sizepad(const float* __restrict__ size, float* __restrict__ out,
                          int B, int T, int SP) {
    int i = blockIdx.x * blockDim.x + threadIdx.x;
    if (i >= B * SP) return;
    int b = i / SP, s = i % SP;
    out[i] = (s < T) ? size[b * T + s] : 0.f;
}

// ======== QKV core: 128x128 4-wave, BK=64, single-buffer 32KB LDS ========
template<bool ROUTE>
__global__ __launch_bounds__(256) void k_gemm4(
    const short* __restrict__ A, const short* __restrict__ Bw,
    const float* __restrict__ bb0, const float* __restrict__ bb1, const float* __restrict__ bb2,
    short* __restrict__ o0, short* __restrict__ o1, short* __restrict__ o2,
    float* __restrict__ Cf, int M, int N, int K, int Ntiles, float alpha0) {

    __shared__ short As[128 * 64];
    __shared__ short Bs[128 * 64];

    int nwg = gridDim.x, orig = blockIdx.x;
    int qq = nwg >> 3, rr = nwg & 7;
    int xcd = orig & 7, pos = orig >> 3;
    int wg = (xcd < rr ? xcd * (qq + 1) : rr * (qq + 1) + (xcd - rr) * qq) + pos;
    int bx = wg % Ntiles, by = wg / Ntiles;
    int row0 = by * 128, col0 = bx * 128;

    int tid = threadIdx.x;
    int lane = tid & 63, wave = tid >> 6;
    int wr = wave >> 1, wc = wave & 1;
    int lr = lane & 15, lg = lane >> 4;

    f32x4 acc[4][4];
    #pragma unroll
    for (int i = 0; i < 4; i++)
        #pragma unroll
        for (int j = 0; j < 4; j++)
            #pragma unroll
            for (int q = 0; q < 4; q++) acc[i][j][q] = 0.f;

    for (int k0 = 0; k0 < K; k0 += 64) {
        __syncthreads();
        #pragma unroll
        for (int i = 0; i < 4; ++i) {
            int cw = i * 256 + wave * 64;
            int c = cw + lane;
            int r = c >> 3;
            int cby = ((c & 7) * 16) ^ ((r & 7) << 4);
            int ra = row0 + r; ra = ra < M ? ra : M - 1;
            gload16((const char*)(A + (long)ra * K + k0) + cby, &As[cw * 8]);
            int rb = col0 + r; rb = rb < N ? rb : N - 1;
            gload16((const char*)(Bw + (long)rb * K + k0) + cby, &Bs[cw * 8]);
        }
        __syncthreads();
        #pragma unroll
        for (int ks = 0; ks < 2; ++ks) {
            s16x8 af[4], bfr[4];
            #pragma unroll
            for (int i = 0; i < 4; ++i) {
                int r = wr * 64 + i * 16 + lr;
                af[i] = *(const s16x8*)((const char*)As + r * 128 +
                        (((ks << 6) + (lg << 4)) ^ ((r & 7) << 4)));
            }
            #pragma unroll
            for (int j = 0; j < 4; ++j) {
                int r = wc * 64 + j * 16 + lr;
                bfr[j] = *(const s16x8*)((const char*)Bs + r * 128 +
                         (((ks << 6) + (lg << 4)) ^ ((r & 7) << 4)));
            }
            #pragma unroll
            for (int i = 0; i < 4; ++i)
                #pragma unroll
                for (int j = 0; j < 4; ++j)
                    acc[i][j] = MFMA16(af[i], bfr[j], acc[i][j]);
        }
    }

    #pragma unroll
    for (int i = 0; i < 4; i++) {
        int grow0 = row0 + wr * 64 + i * 16 + lg * 4;
        #pragma unroll
        for (int j = 0; j < 4; j++) {
            int gc = col0 + wc * 64 + j * 16 + lr;
            if (gc >= N) continue;
            if (ROUTE) {
                int which = gc >> 10, lc = gc & 1023;
                float bias = (which == 0 ? bb0 : which == 1 ? bb1 : bb2)[lc];
                float alpha = (which == 0) ? alpha0 : 1.0f;
                short* op = (which == 0 ? o0 : which == 1 ? o1 : o2);
                #pragma unroll
                for (int q = 0; q < 4; ++q) {
                    int r2 = grow0 + q;
                    if (r2 < M) op[(long)r2 * 1024 + lc] = f2b((acc[i][j][q] + bias) * alpha);
                }
            } else {
                float bias = bb0[gc];
                #pragma unroll
                for (int q = 0; q < 4; ++q) {
                    int r2 = grow0 + q;
                    if (r2 < M) Cf[(long)r2 * N + gc] = acc[i][j][q] + bias;
                }
            }
        }
    }
}

// ======== latency-hiding core: BK=32, 2-deep dbuf in 32KB LDS (att/proj) ====
__device__ __forceinline__ void core32(
    const short* __restrict__ A, const short* __restrict__ Bw,
    int M, int N, int K, int row0, int col0,
    short* AS, short* BS,
    f32x4 acc[4][4]) {
    int tid = threadIdx.x;
    int lane = tid & 63, wave = tid >> 6;
    int wr = wave >> 1, wc = wave & 1;
    int lr = lane & 15, lg = lane >> 4;

    const char* ga[2]; const char* gb[2]; int ldo[2];
    #pragma unroll
    for (int j = 0; j < 2; ++j) {
        int ch = j * 256 + wave * 64 + lane;
        int r = ch >> 2, slot = ch & 3;
        int cby = (slot << 4) ^ (((r >> 1) & 3) << 4);
        int ra = row0 + r; ra = ra < M ? ra : M - 1;
        int rb = col0 + r; rb = rb < N ? rb : N - 1;
        ga[j] = (const char*)(A + (long)ra * K) + cby;
        gb[j] = (const char*)(Bw + (long)rb * K) + cby;
        ldo[j] = ch * 8;
    }
    #pragma unroll
    for (int i = 0; i < 4; i++)
        #pragma unroll
        for (int j = 0; j < 4; j++)
            #pragma unroll
            for (int q = 0; q < 4; q++) acc[i][j][q] = 0.f;

    #pragma unroll
    for (int j = 0; j < 2; ++j) {
        gload16(ga[j], AS + ldo[j]);
        gload16(gb[j], BS + ldo[j]);
        ga[j] += 64; gb[j] += 64;
    }

    int nt = K >> 5;
    for (int t = 0; t < nt; ++t) {
        int cur = t & 1;
        asm volatile("s_waitcnt vmcnt(0)" ::: "memory");
        __builtin_amdgcn_s_barrier();
        if (t + 1 < nt) {
            short* Ad = AS + (cur ^ 1) * 4096;
            short* Bd = BS + (cur ^ 1) * 4096;
            #pragma unroll
            for (int j = 0; j < 2; ++j) {
                gload16(ga[j], Ad + ldo[j]);
                gload16(gb[j], Bd + ldo[j]);
                ga[j] += 64; gb[j] += 64;
            }
        }
        const short* Ab2 = AS + cur * 4096;
        const short* Bb2 = BS + cur * 4096;
        s16x8 af[4], bfr[4];
        #pragma unroll
        for (int i = 0; i < 4; ++i) {
            int r = wr * 64 + i * 16 + lr;
            af[i] = *(const s16x8*)((const char*)Ab2 + r * 64 +
                    ((lg << 4) ^ (((r >> 1) & 3) << 4)));
        }
        #pragma unroll
        for (int j = 0; j < 4; ++j) {
            int r = wc * 64 + j * 16 + lr;
            bfr[j] = *(const s16x8*)((const char*)Bb2 + r * 64 +
                     ((lg << 4) ^ (((r >> 1) & 3) << 4)));
        }
        __builtin_amdgcn_s_setprio(1);
        #pragma unroll
        for (int i = 0; i < 4; ++i)
            #pragma unroll
            for (int j = 0; j < 4; ++j)
                acc[i][j] = MFMA16(af[i], bfr[j], acc[i][j]);
        __builtin_amdgcn_s_setprio(0);
    }
}

// proj on core32 (fp32 epilogue + bias)
__global__ __launch_bounds__(256) void k_proj32(
    const short* __restrict__ A, const short* __restrict__ Bw,
    const float* __restrict__ bias, float* __restrict__ Cf,
    int M, int N, int K, int Ntiles) {
    __shared__ short AS[2][128 * 32];
    __shared__ short BS[2][128 * 32];

    int nwg = gridDim.x, orig = blockIdx.x;
    int qq = nwg >> 3, rr = nwg & 7;
    int xcd = orig & 7, pos = orig >> 3;
    int wg = (xcd < rr ? xcd * (qq + 1) : rr * (qq + 1) + (xcd - rr) * qq) + pos;
    int bx = wg % Ntiles, by = wg / Ntiles;
    int row0 = by * 128, col0 = bx * 128;

    int tid = threadIdx.x;
    int lane = tid & 63, wave = tid >> 6;
    int wr = wave >> 1, wc = wave & 1;
    int lr = lane & 15, lg = lane >> 4;

    f32x4 acc[4][4];
    core32(A, Bw, M, N, K, row0, col0, &AS[0][0], &BS[0][0], acc);

    #pragma unroll
    for (int i = 0; i < 4; i++) {
        int grow0 = row0 + wr * 64 + i * 16 + lg * 4;
        #pragma unroll
        for (int j = 0; j < 4; j++) {
            int gc = col0 + wc * 64 + j * 16 + lr;
            if (gc >= N) continue;
            float bv = bias[gc];
            #pragma unroll
            for (int q = 0; q < 4; ++q) {
                int r2 = grow0 + q;
                if (r2 < M) Cf[(long)r2 * N + gc] = acc[i][j][q] + bv;
            }
        }
    }
}

// ---------------- att partials: core32, fp32 epilogue ----------------
__global__ __launch_bounds__(256) void k_att(
    const short* __restrict__ q, const short* __restrict__ k,
    float* __restrict__ attp, int T, int E) {
    __shared__ short AS[2][128 * 32];
    __shared__ short BS[2][128 * 32];
    int z = blockIdx.z;
    const short* Ab = q + (long)z * T * E;
    const short* Bb = k + (long)z * T * E;
    float* Cf = attp + (long)z * T * T;
    int row0 = blockIdx.y * 128, col0 = blockIdx.x * 128;

    int tid = threadIdx.x;
    int lane = tid & 63, wave = tid >> 6;
    int wr = wave >> 1, wc = wave & 1;
    int lr = lane & 15, lg = lane >> 4;

    f32x4 acc[4][4];
    core32(Ab, Bb, T, T, E, row0, col0, &AS[0][0], &BS[0][0], acc);

    #pragma unroll
    for (int i = 0; i < 4; i++) {
        int rbase = row0 + wr * 64 + i * 16 + lg * 4;
        #pragma unroll
        for (int j = 0; j < 4; j++) {
            int c = col0 + wc * 64 + j * 16 + lr;
            if (c >= T) continue;
            #pragma unroll
            for (int q2 = 0; q2 < 4; q2++) {
                int r = rbase + q2;
                if (r >= T) continue;
                Cf[(long)r * T + c] = acc[i][j][q2];
            }
        }
    }
}

// ---------------- mean over heads of K ----------------
__global__ void k_mean_keys8(const short* __restrict__ Kb, float* __restrict__ out, int BT) {
    int i = blockIdx.x * blockDim.x + threadIdx.x;
    if (i >= BT * 8) return;
    int bt = i >> 3, d0 = (i & 7) * 8;
    const short* p = Kb + (long)bt * 1024 + d0;
    float s[8] = {0.f, 0.f, 0.f, 0.f, 0.f, 0.f, 0.f, 0.f};
    #pragma unroll
    for (int h = 0; h < 16; ++h) {
        s16x8 v = *(const s16x8*)(p + h * 64);
        #pragma unroll
        for (int j = 0; j < 8; ++j) s[j] += b2f(v[j]);
    }
    float4 o0 = {s[0] * 0.0625f, s[1] * 0.0625f, s[2] * 0.0625f, s[3] * 0.0625f};
    float4 o1 = {s[4] * 0.0625f, s[5] * 0.0625f, s[6] * 0.0625f, s[7] * 0.0625f};
    *(float4*)(out + (long)bt * 64 + d0) = o0;
    *(float4*)(out + (long)bt * 64 + d0 + 4) = o1;
}

// ---------------- reduce att_score partials over batch ----------------
__global__ void k_att_reduce(const float* __restrict__ part, float* __restrict__ out,
                             int n, int nb, long stride) {
    int i = blockIdx.x * blockDim.x + threadIdx.x;
    if (i >= n) return;
    float s = 0.f;
    for (int b = 0; b < nb; ++b) s += part[(long)b * stride + i];
    out[i] = s * 0.002707606174062286f;  // ln(2)/256 compensates log2e folded into q
}

// ---------------- V transpose + size pre-scale ----------------
__global__ __launch_bounds__(256) void k_vtrans(const short* __restrict__ v, short* __restrict__ vt,
                                                const float* __restrict__ szp,
                                                int B, int T, int H, int TP, int SP) {
    int b = blockIdx.z, h = blockIdx.y, t0 = blockIdx.x * 64;
    __shared__ short Vs[64][68];
    __shared__ float Szs[64];
    int tid = threadIdx.x;
    if (tid < 64) Szs[tid] = szp[b * SP + t0 + tid];
    for (int c = tid; c < 512; c += 256) {
        int r = c >> 3, m = c & 7;
        s16x8 val = {0,0,0,0,0,0,0,0};
        if (t0 + r < T) val = *(const s16x8*)(v + ((long)(b * T + t0 + r)) * (H * 64) + h * 64 + m * 8);
        *(s16x8*)&Vs[r][m * 8] = val;
    }
    __syncthreads();
    for (int c = tid; c < 512; c += 256) {
        int d = c >> 3, mw = c & 7;
        s16x8 o;
        #pragma unroll
        for (int j = 0; j < 8; j++) o[j] = f2b(b2f(Vs[mw * 8 + j][d]) * Szs[mw * 8 + j]);
        *(s16x8*)(vt + ((long)((b * H + h) * 64 + d)) * TP + t0 + mw * 8) = o;
    }
}

// ---------------- flash attention v6: QBLK=64 (tail-fit), lsum via 65th-column MFMA ----------------
// grid 2560 blocks; per wave ONE 16-row q group. LDS ~28KB.
__global__ __launch_bounds__(256) void k_flash(
    const short* __restrict__ Q, const short* __restrict__ Kb, const short* __restrict__ VT,
    const float* __restrict__ szp, short* __restrict__ Ctx,
    int B, int T, int E, int H, int SP, int TP, int NTQ) {
    int nwg = gridDim.x;
    int cpx = nwg >> 3;
    int wg = (blockIdx.x & 7) * cpx + (blockIdx.x >> 3);
    int tq = wg % NTQ, h = (wg / NTQ) % H, b = wg / (NTQ * H);
    int t0 = tq * 64;

    __shared__ short Ks[64][68];
    __shared__ short Vt[80][68];      // rows 0-63: V'^T; row 64: size; rows 65-79: zero
    __shared__ short Ps[4][16][68];   // one 16-row P tile per wave
    int tid = threadIdx.x, wid = tid >> 6, lane = tid & 63;
    int lr = lane & 15, lg = lane >> 4;

    for (int c = tid; c < 15 * 68; c += 256) Vt[65 + c / 68][c % 68] = 0;

    // Q fragments: wave wid owns q rows t0 + wid*16 .. +15
    s16x8 aqf[2];
    {
        int t = t0 + wid * 16 + lr; t = t < T ? t : T - 1;
        #pragma unroll
        for (int ks = 0; ks < 2; ++ks)
            aqf[ks] = *(const s16x8*)(Q + ((long)b * T + t) * E + h * 64 + ks * 32 + lg * 8);
    }

    const short* kb  = Kb + (long)b * T * E + h * 64;
    const short* vtb = VT + ((long)(b * H + h)) * 64 * TP;

    int c0 = tid, c1 = tid + 256;
    int r0 = c0 >> 3, m0 = c0 & 7, r1 = c1 >> 3, m1 = c1 & 7;
    s16x8 kreg0, kreg1, vreg0, vreg1;
    float szreg = 0.f;

    {
        int s = r0; s = s < T ? s : T - 1;
        kreg0 = *(const s16x8*)(kb + (long)s * E + m0 * 8);
        s = r1; s = s < T ? s : T - 1;
        kreg1 = *(const s16x8*)(kb + (long)s * E + m1 * 8);
        vreg0 = *(const s16x8*)(vtb + (long)r0 * TP + 0 + m0 * 8);
        vreg1 = *(const s16x8*)(vtb + (long)r1 * TP + 0 + m1 * 8);
        if (tid < 64) szreg = szp[b * SP + 0 + tid];
    }

    float mreg[4];
    f32x4 o[5];                       // jd 0-3: O accum; jd 4: lsum (col 64)
    #pragma unroll
    for (int q = 0; q < 4; q++) mreg[q] = -INFINITY;
    #pragma unroll
    for (int jd = 0; jd < 5; jd++)
        #pragma unroll
        for (int q = 0; q < 4; q++) o[jd][q] = 0.f;

    for (int s0 = 0; s0 < T; s0 += 64) {
        *(s16x8*)&Ks[r0][m0 * 8] = kreg0;
        *(s16x8*)&Ks[r1][m1 * 8] = kreg1;
        *(s16x8*)&Vt[r0][m0 * 8] = vreg0;
        *(s16x8*)&Vt[r1][m1 * 8] = vreg1;
        if (tid < 64) Vt[64][tid] = f2b(szreg);
        __syncthreads();

        if (s0 + 64 < T) {
            int sn = s0 + 64;
            int s = sn + r0; s = s < T ? s : T - 1;
            kreg0 = *(const s16x8*)(kb + (long)s * E + m0 * 8);
            s = sn + r1; s = s < T ? s : T - 1;
            kreg1 = *(const s16x8*)(kb + (long)s * E + m1 * 8);
            vreg0 = *(const s16x8*)(vtb + (long)r0 * TP + sn + m0 * 8);
            vreg1 = *(const s16x8*)(vtb + (long)r1 * TP + sn + m1 * 8);
            if (tid < 64) szreg = szp[b * SP + sn + tid];
        }

        f32x4 sf[4];
        #pragma unroll
        for (int j = 0; j < 4; j++)
            #pragma unroll
            for (int q = 0; q < 4; q++) sf[j][q] = 0.f;
        __builtin_amdgcn_s_setprio(1);
        #pragma unroll
        for (int ks = 0; ks < 2; ++ks)
            #pragma unroll
            for (int j = 0; j < 4; j++) {
                s16x8 bk = *(const s16x8*)&Ks[j * 16 + lr][ks * 32 + lg * 8];
                sf[j] = MFMA16(aqf[ks], bk, sf[j]);
            }
        __builtin_amdgcn_s_setprio(0);

        float tmax[4];
        #pragma unroll
        for (int q = 0; q < 4; q++)
            tmax[q] = fmaxf(fmaxf(sf[0][q], sf[1][q]), fmaxf(sf[2][q], sf[3][q]));
        int ok = 1;
        #pragma unroll
        for (int q = 0; q < 4; q++) ok &= (tmax[q] <= mreg[q] + 11.0f) ? 1 : 0;
        if (!__all(ok)) {
            #pragma unroll
            for (int q = 0; q < 4; q++) {
                #pragma unroll
                for (int msk = 1; msk < 16; msk <<= 1)
                    tmax[q] = fmaxf(tmax[q], __shfl_xor(tmax[q], msk));
                float mn = fmaxf(mreg[q], tmax[q]);
                float al = exp2f(mreg[q] - mn);
                mreg[q] = mn;
                #pragma unroll
                for (int jd = 0; jd < 5; jd++) o[jd][q] *= al;
            }
        }
        #pragma unroll
        for (int j = 0; j < 4; j++)
            #pragma unroll
            for (int q = 0; q < 4; q++)
                Ps[wid][lg * 4 + q][j * 16 + lr] = f2b(exp2f(sf[j][q] - mreg[q]));

        __builtin_amdgcn_s_setprio(1);
        #pragma unroll
        for (int ks = 0; ks < 2; ++ks) {
            s16x8 ap = *(const s16x8*)&Ps[wid][lr][ks * 32 + lg * 8];
            #pragma unroll
            for (int jd = 0; jd < 5; jd++) {
                s16x8 bv = *(const s16x8*)&Vt[jd * 16 + lr][ks * 32 + lg * 8];
                o[jd] = MFMA16(ap, bv, o[jd]);
            }
        }
        __builtin_amdgcn_s_setprio(0);
        __syncthreads();
    }

    short* cb = Ctx + ((long)b * T + t0) * E + h * 64;
    #pragma unroll
    for (int q = 0; q < 4; q++) {
        float s = __shfl(o[4][q], lane & 48);   // lsum in col 64 (lr==0 of jd=4 tile)
        int t = wid * 16 + lg * 4 + q;
        if (t0 + t >= T) continue;
        float inv = 1.f / s;
        #pragma unroll
        for (int jd = 0; jd < 4; jd++)
            cb[(long)t * E + jd * 16 + lr] = f2b(o[jd][q] * inv);
    }
}

extern "C" void kernel_launch(void* const* d_in, const int* in_sizes, int n_in,
                              void* d_out, int out_size, void* d_ws, size_t ws_size,
                              hipStream_t stream) {
    (void)in_sizes; (void)n_in; (void)out_size; (void)ws_size;
    const int B = 16, T = 577, E = 1024, H = 16;
    const int SP = 640, TP = 640;
    const float* hs   = (const float*)d_in[0];
    const float* size = (const float*)d_in[1];
    const float* wq   = (const float*)d_in[2];
    const float* bq   = (const float*)d_in[3];
    const float* wk   = (const float*)d_in[4];
    const float* bk   = (const float*)d_in[5];
    const float* wv   = (const float*)d_in[6];
    const float* bv   = (const float*)d_in[7];
    const float* wo   = (const float*)d_in[8];
    const float* bo   = (const float*)d_in[9];

    float* out_attn = (float*)d_out;                  // B*T*E
    float* out_mk   = out_attn + (long)B * T * E;     // B*T*D
    float* out_as   = out_mk + (long)B * T * 64;      // T*T

    long nBTE = (long)B * T * E;
    long nEE  = (long)E * E;
    char* ws = (char*)d_ws;
    short* hs_b  = (short*)ws; ws += nBTE * 2;
    short* wq_b  = (short*)ws; ws += nEE * 2;   // wq|wk|wv|wo contiguous
    short* wk_b  = (short*)ws; ws += nEE * 2;
    short* wv_b  = (short*)ws; ws += nEE * 2;
    short* wo_b  = (short*)ws; ws += nEE * 2;
    short* q_b   = (short*)ws; ws += nBTE * 2;
    short* k_b   = (short*)ws; ws += nBTE * 2;
    short* v_b   = (short*)ws; ws += nBTE * 2;
    short* ctx_b = (short*)ws; ws += nBTE * 2;
    float* szpad = (float*)ws; ws += (long)B * SP * 4;
    float* att_p = (float*)ws; ws += (long)B * T * T * 4;
    short* vt = (short*)att_p;   // aliases att_p, written after reduce consumed it

    k_f32_to_bf16<<<2048, 256, 0, stream>>>(hs, hs_b, nBTE);
    {
        dim3 gw((nEE / 4 + 255) / 256, 4);
        k_wconv4<<<gw, 256, 0, stream>>>(wq, wk, wv, wo, wq_b, nEE);
    }
    k_sizepad<<<(B * SP + 255) / 256, 256, 0, stream>>>(size, szpad, B, T, SP);

    int M = B * T;  // 9232
    {
        int Mtiles = (M + 127) / 128, Ntiles = 3072 / 128;   // 73 x 24 = 1752 blocks
        k_gemm4<true><<<Mtiles * Ntiles, 256, 0, stream>>>(
            hs_b, wq_b, bq, bk, bv, q_b, k_b, v_b, nullptr, M, 3072, E, Ntiles,
            0.18033688011112042f);  // 0.125 * log2(e)
    }

    dim3 g_att((T + 127) / 128, (T + 127) / 128, B);
    k_att<<<g_att, dim3(256), 0, stream>>>(q_b, k_b, att_p, T, E);
    k_att_reduce<<<((T * T) + 255) / 256, 256, 0, stream>>>(att_p, out_as, T * T, B, (long)T * T);

    dim3 g_vt((T + 63) / 64, H, B);
    k_vtrans<<<g_vt, dim3(256), 0, stream>>>(v_b, vt, szpad, B, T, H, TP, SP);

    k_mean_keys8<<<((B * T * 8) + 255) / 256, 256, 0, stream>>>(k_b, out_mk, B * T);

    const int NTQ = (T + 63) / 64;   // 10 -> 2560 blocks (%8==0)
    int nfl = NTQ * H * B;
    k_flash<<<nfl, dim3(256), 0, stream>>>(q_b, k_b, vt, szpad, ctx_b, B, T, E, H, SP, TP, NTQ);

    {
        int Mtiles = (M + 127) / 128, Ntiles = 1024 / 128;   // 73 x 8 = 584 blocks
        k_proj32<<<Mtiles * Ntiles, 256, 0, stream>>>(
            ctx_b, wo_b, bo, out_attn, M, 1024, E, Ntiles);
    }
}

// Round 19
// 274.981 us; speedup vs baseline: 1.0585x; 1.0539x over previous
//
#include <hip/hip_runtime.h>
#include <hip/hip_bf16.h>
#include <math.h>

typedef __attribute__((ext_vector_type(8))) short s16x8;
typedef __attribute__((ext_vector_type(4))) short s16x4;
typedef __attribute__((ext_vector_type(4))) float f32x4;
typedef __attribute__((ext_vector_type(8))) __bf16 bf16x8;

#define MFMA16(a, b, c) __builtin_amdgcn_mfma_f32_16x16x32_bf16( \
    __builtin_bit_cast(bf16x8, (a)), __builtin_bit_cast(bf16x8, (b)), (c), 0, 0, 0)

__device__ __forceinline__ short f2b(float f) {
    __bf16 h = (__bf16)f;
    return __builtin_bit_cast(short, h);
}
__device__ __forceinline__ float b2f(short b) {
    union { unsigned u; float f; } x;
    x.u = ((unsigned)(unsigned short)b) << 16;
    return x.f;
}

__device__ __forceinline__ void gload16(const void* g, void* l) {
    __builtin_amdgcn_global_load_lds(
        (const __attribute__((address_space(1))) unsigned int*)g,
        (__attribute__((address_space(3))) unsigned int*)l, 16, 0, 0);
}

// ---------------- fp32 -> bf16 convert (hidden states) ----------------
__global__ void k_f32_to_bf16(const float* __restrict__ in, short* __restrict__ out, long n) {
    long i = ((long)blockIdx.x * blockDim.x + threadIdx.x) * 4;
    long stride = (long)gridDim.x * blockDim.x * 4;
    for (; i < n; i += stride) {
        float4 v = *(const float4*)(in + i);
        s16x4 o = { f2b(v.x), f2b(v.y), f2b(v.z), f2b(v.w) };
        *(s16x4*)(out + i) = o;
    }
}

// ---------------- fused 4-weight convert ----------------
__global__ void k_wconv4(const float* __restrict__ w0, const float* __restrict__ w1,
                         const float* __restrict__ w2, const float* __restrict__ w3,
                         short* __restrict__ out, long n) {
    int wsel = blockIdx.y;
    const float* src = (wsel == 0) ? w0 : (wsel == 1) ? w1 : (wsel == 2) ? w2 : w3;
    short* dst = out + (long)wsel * n;
    long i = ((long)blockIdx.x * blockDim.x + threadIdx.x) * 4;
    if (i >= n) return;
    float4 v = *(const float4*)(src + i);
    s16x4 o = { f2b(v.x), f2b(v.y), f2b(v.z), f2b(v.w) };
    *(s16x4*)(dst + i) = o;
}

// ---------------- raw size with 0-padding ----------------
__global__ void k_sizepad(const float* __restrict__ size, float* __restrict__ out,
                          int B, int T, int SP) {
    int i = blockIdx.x * blockDim.x + threadIdx.x;
    if (i >= B * SP) return;
    int b = i / SP, s = i % SP;
    out[i] = (s < T) ? size[b * T + s] : 0.f;
}

// ======== QKV: 128x128 tile, 8 waves x (32x64) sub-tiles, BK=64, 32KB LDS ========
// acc[2][4] = 32 VGPR -> fits the 64-VGPR cap of (512,4) [= 4 blocks/CU, 8 waves/SIMD].
// Occupancy 16 -> 32 waves/CU; LDS 4x32KB = 128KB.
template<bool ROUTE>
__global__ __launch_bounds__(512, 4) void k_gemm8w(
    const short* __restrict__ A, const short* __restrict__ Bw,
    const float* __restrict__ bb0, const float* __restrict__ bb1, const float* __restrict__ bb2,
    short* __restrict__ o0, short* __restrict__ o1, short* __restrict__ o2,
    float* __restrict__ Cf, int M, int N, int K, int Ntiles, float alpha0) {

    __shared__ short As[128 * 64];
    __shared__ short Bs[128 * 64];

    int nwg = gridDim.x, orig = blockIdx.x;
    int qq = nwg >> 3, rr = nwg & 7;
    int xcd = orig & 7, pos = orig >> 3;
    int wg = (xcd < rr ? xcd * (qq + 1) : rr * (qq + 1) + (xcd - rr) * qq) + pos;
    int bx = wg % Ntiles, by = wg / Ntiles;
    int row0 = by * 128, col0 = bx * 128;

    int tid = threadIdx.x;
    int lane = tid & 63, wave = tid >> 6;   // 0..7
    int wr = wave >> 1, wc = wave & 1;      // 4 row-slabs x 2 col-halves
    int lr = lane & 15, lg = lane >> 4;

    f32x4 acc[2][4];
    #pragma unroll
    for (int i = 0; i < 2; i++)
        #pragma unroll
        for (int j = 0; j < 4; j++)
            #pragma unroll
            for (int q = 0; q < 4; q++) acc[i][j][q] = 0.f;

    for (int k0 = 0; k0 < K; k0 += 64) {
        __syncthreads();
        // 1024 chunks of A + 1024 of B over 512 threads (2 each per matrix)
        #pragma unroll
        for (int jj = 0; jj < 2; ++jj) {
            int ch = tid + jj * 512;
            int r = ch >> 3;
            int cby = ((ch & 7) * 16) ^ ((r & 7) << 4);   // pre-swizzled source byte col
            int ra = row0 + r; ra = ra < M ? ra : M - 1;
            gload16((const char*)(A + (long)ra * K + k0) + cby, &As[ch * 8]);
            int rb = col0 + r; rb = rb < N ? rb : N - 1;
            gload16((const char*)(Bw + (long)rb * K + k0) + cby, &Bs[ch * 8]);
        }
        __syncthreads();
        #pragma unroll
        for (int ks = 0; ks < 2; ++ks) {
            s16x8 af[2];
            #pragma unroll
            for (int i = 0; i < 2; ++i) {
                int r = wr * 32 + i * 16 + lr;
                af[i] = *(const s16x8*)((const char*)As + r * 128 +
                        (((ks << 6) + (lg << 4)) ^ ((r & 7) << 4)));
            }
            #pragma unroll
            for (int j = 0; j < 4; ++j) {                // 1 live B-fragment at a time
                int r = wc * 64 + j * 16 + lr;
                s16x8 bfr = *(const s16x8*)((const char*)Bs + r * 128 +
                            (((ks << 6) + (lg << 4)) ^ ((r & 7) << 4)));
                acc[0][j] = MFMA16(af[0], bfr, acc[0][j]);
                acc[1][j] = MFMA16(af[1], bfr, acc[1][j]);
            }
        }
    }

    #pragma unroll
    for (int i = 0; i < 2; i++) {
        int grow0 = row0 + wr * 32 + i * 16 + lg * 4;
        #pragma unroll
        for (int j = 0; j < 4; j++) {
            int gc = col0 + wc * 64 + j * 16 + lr;
            if (gc >= N) continue;
            if (ROUTE) {
                int which = gc >> 10, lc = gc & 1023;
                float bias = (which == 0 ? bb0 : which == 1 ? bb1 : bb2)[lc];
                float alpha = (which == 0) ? alpha0 : 1.0f;
                short* op = (which == 0 ? o0 : which == 1 ? o1 : o2);
                #pragma unroll
                for (int q = 0; q < 4; ++q) {
                    int r2 = grow0 + q;
                    if (r2 < M) op[(long)r2 * 1024 + lc] = f2b((acc[i][j][q] + bias) * alpha);
                }
            } else {
                float bias = bb0[gc];
                #pragma unroll
                for (int q = 0; q < 4; ++q) {
                    int r2 = grow0 + q;
                    if (r2 < M) Cf[(long)r2 * N + gc] = acc[i][j][q] + bias;
                }
            }
        }
    }
}

// ======== latency-hiding core: BK=32, 2-deep dbuf in 32KB LDS (att/proj) ====
__device__ __forceinline__ void core32(
    const short* __restrict__ A, const short* __restrict__ Bw,
    int M, int N, int K, int row0, int col0,
    short* AS, short* BS,
    f32x4 acc[4][4]) {
    int tid = threadIdx.x;
    int lane = tid & 63, wave = tid >> 6;
    int wr = wave >> 1, wc = wave & 1;
    int lr = lane & 15, lg = lane >> 4;

    const char* ga[2]; const char* gb[2]; int ldo[2];
    #pragma unroll
    for (int j = 0; j < 2; ++j) {
        int ch = j * 256 + wave * 64 + lane;
        int r = ch >> 2, slot = ch & 3;
        int cby = (slot << 4) ^ (((r >> 1) & 3) << 4);
        int ra = row0 + r; ra = ra < M ? ra : M - 1;
        int rb = col0 + r; rb = rb < N ? rb : N - 1;
        ga[j] = (const char*)(A + (long)ra * K) + cby;
        gb[j] = (const char*)(Bw + (long)rb * K) + cby;
        ldo[j] = ch * 8;
    }
    #pragma unroll
    for (int i = 0; i < 4; i++)
        #pragma unroll
        for (int j = 0; j < 4; j++)
            #pragma unroll
            for (int q = 0; q < 4; q++) acc[i][j][q] = 0.f;

    #pragma unroll
    for (int j = 0; j < 2; ++j) {
        gload16(ga[j], AS + ldo[j]);
        gload16(gb[j], BS + ldo[j]);
        ga[j] += 64; gb[j] += 64;
    }

    int nt = K >> 5;
    for (int t = 0; t < nt; ++t) {
        int cur = t & 1;
        asm volatile("s_waitcnt vmcnt(0)" ::: "memory");
        __builtin_amdgcn_s_barrier();
        if (t + 1 < nt) {
            short* Ad = AS + (cur ^ 1) * 4096;
            short* Bd = BS + (cur ^ 1) * 4096;
            #pragma unroll
            for (int j = 0; j < 2; ++j) {
                gload16(ga[j], Ad + ldo[j]);
                gload16(gb[j], Bd + ldo[j]);
                ga[j] += 64; gb[j] += 64;
            }
        }
        const short* Ab2 = AS + cur * 4096;
        const short* Bb2 = BS + cur * 4096;
        s16x8 af[4], bfr[4];
        #pragma unroll
        for (int i = 0; i < 4; ++i) {
            int r = wr * 64 + i * 16 + lr;
            af[i] = *(const s16x8*)((const char*)Ab2 + r * 64 +
                    ((lg << 4) ^ (((r >> 1) & 3) << 4)));
        }
        #pragma unroll
        for (int j = 0; j < 4; ++j) {
            int r = wc * 64 + j * 16 + lr;
            bfr[j] = *(const s16x8*)((const char*)Bb2 + r * 64 +
                     ((lg << 4) ^ (((r >> 1) & 3) << 4)));
        }
        __builtin_amdgcn_s_setprio(1);
        #pragma unroll
        for (int i = 0; i < 4; ++i)
            #pragma unroll
            for (int j = 0; j < 4; ++j)
                acc[i][j] = MFMA16(af[i], bfr[j], acc[i][j]);
        __builtin_amdgcn_s_setprio(0);
    }
}

// proj on core32 (fp32 epilogue + bias)
__global__ __launch_bounds__(256) void k_proj32(
    const short* __restrict__ A, const short* __restrict__ Bw,
    const float* __restrict__ bias, float* __restrict__ Cf,
    int M, int N, int K, int Ntiles) {
    __shared__ short AS[2][128 * 32];
    __shared__ short BS[2][128 * 32];

    int nwg = gridDim.x, orig = blockIdx.x;
    int qq = nwg >> 3, rr = nwg & 7;
    int xcd = orig & 7, pos = orig >> 3;
    int wg = (xcd < rr ? xcd * (qq + 1) : rr * (qq + 1) + (xcd - rr) * qq) + pos;
    int bx = wg % Ntiles, by = wg / Ntiles;
    int row0 = by * 128, col0 = bx * 128;

    int tid = threadIdx.x;
    int lane = tid & 63, wave = tid >> 6;
    int wr = wave >> 1, wc = wave & 1;
    int lr = lane & 15, lg = lane >> 4;

    f32x4 acc[4][4];
    core32(A, Bw, M, N, K, row0, col0, &AS[0][0], &BS[0][0], acc);

    #pragma unroll
    for (int i = 0; i < 4; i++) {
        int grow0 = row0 + wr * 64 + i * 16 + lg * 4;
        #pragma unroll
        for (int j = 0; j < 4; j++) {
            int gc = col0 + wc * 64 + j * 16 + lr;
            if (gc >= N) continue;
            float bv = bias[gc];
            #pragma unroll
            for (int q = 0; q < 4; ++q) {
                int r2 = grow0 + q;
                if (r2 < M) Cf[(long)r2 * N + gc] = acc[i][j][q] + bv;
            }
        }
    }
}

// ---------------- att partials: core32, fp32 epilogue ----------------
__global__ __launch_bounds__(256) void k_att(
    const short* __restrict__ q, const short* __restrict__ k,
    float* __restrict__ attp, int T, int E) {
    __shared__ short AS[2][128 * 32];
    __shared__ short BS[2][128 * 32];
    int z = blockIdx.z;
    const short* Ab = q + (long)z * T * E;
    const short* Bb = k + (long)z * T * E;
    float* Cf = attp + (long)z * T * T;
    int row0 = blockIdx.y * 128, col0 = blockIdx.x * 128;

    int tid = threadIdx.x;
    int lane = tid & 63, wave = tid >> 6;
    int wr = wave >> 1, wc = wave & 1;
    int lr = lane & 15, lg = lane >> 4;

    f32x4 acc[4][4];
    core32(Ab, Bb, T, T, E, row0, col0, &AS[0][0], &BS[0][0], acc);

    #pragma unroll
    for (int i = 0; i < 4; i++) {
        int rbase = row0 + wr * 64 + i * 16 + lg * 4;
        #pragma unroll
        for (int j = 0; j < 4; j++) {
            int c = col0 + wc * 64 + j * 16 + lr;
            if (c >= T) continue;
            #pragma unroll
            for (int q2 = 0; q2 < 4; q2++) {
                int r = rbase + q2;
                if (r >= T) continue;
                Cf[(long)r * T + c] = acc[i][j][q2];
            }
        }
    }
}

// ---------------- mean over heads of K ----------------
__global__ void k_mean_keys8(const short* __restrict__ Kb, float* __restrict__ out, int BT) {
    int i = blockIdx.x * blockDim.x + threadIdx.x;
    if (i >= BT * 8) return;
    int bt = i >> 3, d0 = (i & 7) * 8;
    const short* p = Kb + (long)bt * 1024 + d0;
    float s[8] = {0.f, 0.f, 0.f, 0.f, 0.f, 0.f, 0.f, 0.f};
    #pragma unroll
    for (int h = 0; h < 16; ++h) {
        s16x8 v = *(const s16x8*)(p + h * 64);
        #pragma unroll
        for (int j = 0; j < 8; ++j) s[j] += b2f(v[j]);
    }
    float4 o0 = {s[0] * 0.0625f, s[1] * 0.0625f, s[2] * 0.0625f, s[3] * 0.0625f};
    float4 o1 = {s[4] * 0.0625f, s[5] * 0.0625f, s[6] * 0.0625f, s[7] * 0.0625f};
    *(float4*)(out + (long)bt * 64 + d0) = o0;
    *(float4*)(out + (long)bt * 64 + d0 + 4) = o1;
}

// ---------------- reduce att_score partials over batch ----------------
__global__ void k_att_reduce(const float* __restrict__ part, float* __restrict__ out,
                             int n, int nb, long stride) {
    int i = blockIdx.x * blockDim.x + threadIdx.x;
    if (i >= n) return;
    float s = 0.f;
    for (int b = 0; b < nb; ++b) s += part[(long)b * stride + i];
    out[i] = s * 0.002707606174062286f;  // ln(2)/256 compensates log2e folded into q
}

// ---------------- V transpose + size pre-scale ----------------
__global__ __launch_bounds__(256) void k_vtrans(const short* __restrict__ v, short* __restrict__ vt,
                                                const float* __restrict__ szp,
                                                int B, int T, int H, int TP, int SP) {
    int b = blockIdx.z, h = blockIdx.y, t0 = blockIdx.x * 64;
    __shared__ short Vs[64][68];
    __shared__ float Szs[64];
    int tid = threadIdx.x;
    if (tid < 64) Szs[tid] = szp[b * SP + t0 + tid];
    for (int c = tid; c < 512; c += 256) {
        int r = c >> 3, m = c & 7;
        s16x8 val = {0,0,0,0,0,0,0,0};
        if (t0 + r < T) val = *(const s16x8*)(v + ((long)(b * T + t0 + r)) * (H * 64) + h * 64 + m * 8);
        *(s16x8*)&Vs[r][m * 8] = val;
    }
    __syncthreads();
    for (int c = tid; c < 512; c += 256) {
        int d = c >> 3, mw = c & 7;
        s16x8 o;
        #pragma unroll
        for (int j = 0; j < 8; j++) o[j] = f2b(b2f(Vs[mw * 8 + j][d]) * Szs[mw * 8 + j]);
        *(s16x8*)(vt + ((long)((b * H + h) * 64 + d)) * TP + t0 + mw * 8) = o;
    }
}

// ---------------- flash attention v6: QBLK=64, lsum via 65th-column MFMA ----------------
__global__ __launch_bounds__(256) void k_flash(
    const short* __restrict__ Q, const short* __restrict__ Kb, const short* __restrict__ VT,
    const float* __restrict__ szp, short* __restrict__ Ctx,
    int B, int T, int E, int H, int SP, int TP, int NTQ) {
    int nwg = gridDim.x;
    int cpx = nwg >> 3;
    int wg = (blockIdx.x & 7) * cpx + (blockIdx.x >> 3);
    int tq = wg % NTQ, h = (wg / NTQ) % H, b = wg / (NTQ * H);
    int t0 = tq * 64;

    __shared__ short Ks[64][68];
    __shared__ short Vt[80][68];
    __shared__ short Ps[4][16][68];
    int tid = threadIdx.x, wid = tid >> 6, lane = tid & 63;
    int lr = lane & 15, lg = lane >> 4;

    for (int c = tid; c < 15 * 68; c += 256) Vt[65 + c / 68][c % 68] = 0;

    s16x8 aqf[2];
    {
        int t = t0 + wid * 16 + lr; t = t < T ? t : T - 1;
        #pragma unroll
        for (int ks = 0; ks < 2; ++ks)
            aqf[ks] = *(const s16x8*)(Q + ((long)b * T + t) * E + h * 64 + ks * 32 + lg * 8);
    }

    const short* kb  = Kb + (long)b * T * E + h * 64;
    const short* vtb = VT + ((long)(b * H + h)) * 64 * TP;

    int c0 = tid, c1 = tid + 256;
    int r0 = c0 >> 3, m0 = c0 & 7, r1 = c1 >> 3, m1 = c1 & 7;
    s16x8 kreg0, kreg1, vreg0, vreg1;
    float szreg = 0.f;

    {
        int s = r0; s = s < T ? s : T - 1;
        kreg0 = *(const s16x8*)(kb + (long)s * E + m0 * 8);
        s = r1; s = s < T ? s : T - 1;
        kreg1 = *(const s16x8*)(kb + (long)s * E + m1 * 8);
        vreg0 = *(const s16x8*)(vtb + (long)r0 * TP + 0 + m0 * 8);
        vreg1 = *(const s16x8*)(vtb + (long)r1 * TP + 0 + m1 * 8);
        if (tid < 64) szreg = szp[b * SP + 0 + tid];
    }

    float mreg[4];
    f32x4 o[5];
    #pragma unroll
    for (int q = 0; q < 4; q++) mreg[q] = -INFINITY;
    #pragma unroll
    for (int jd = 0; jd < 5; jd++)
        #pragma unroll
        for (int q = 0; q < 4; q++) o[jd][q] = 0.f;

    for (int s0 = 0; s0 < T; s0 += 64) {
        *(s16x8*)&Ks[r0][m0 * 8] = kreg0;
        *(s16x8*)&Ks[r1][m1 * 8] = kreg1;
        *(s16x8*)&Vt[r0][m0 * 8] = vreg0;
        *(s16x8*)&Vt[r1][m1 * 8] = vreg1;
        if (tid < 64) Vt[64][tid] = f2b(szreg);
        __syncthreads();

        if (s0 + 64 < T) {
            int sn = s0 + 64;
            int s = sn + r0; s = s < T ? s : T - 1;
            kreg0 = *(const s16x8*)(kb + (long)s * E + m0 * 8);
            s = sn + r1; s = s < T ? s : T - 1;
            kreg1 = *(const s16x8*)(kb + (long)s * E + m1 * 8);
            vreg0 = *(const s16x8*)(vtb + (long)r0 * TP + sn + m0 * 8);
            vreg1 = *(const s16x8*)(vtb + (long)r1 * TP + sn + m1 * 8);
            if (tid < 64) szreg = szp[b * SP + sn + tid];
        }

        f32x4 sf[4];
        #pragma unroll
        for (int j = 0; j < 4; j++)
            #pragma unroll
            for (int q = 0; q < 4; q++) sf[j][q] = 0.f;
        __builtin_amdgcn_s_setprio(1);
        #pragma unroll
        for (int ks = 0; ks < 2; ++ks)
            #pragma unroll
            for (int j = 0; j < 4; j++) {
                s16x8 bk = *(const s16x8*)&Ks[j * 16 + lr][ks * 32 + lg * 8];
                sf[j] = MFMA16(aqf[ks], bk, sf[j]);
            }
        __builtin_amdgcn_s_setprio(0);

        float tmax[4];
        #pragma unroll
        for (int q = 0; q < 4; q++)
            tmax[q] = fmaxf(fmaxf(sf[0][q], sf[1][q]), fmaxf(sf[2][q], sf[3][q]));
        int ok = 1;
        #pragma unroll
        for (int q = 0; q < 4; q++) ok &= (tmax[q] <= mreg[q] + 11.0f) ? 1 : 0;
        if (!__all(ok)) {
            #pragma unroll
            for (int q = 0; q < 4; q++) {
                #pragma unroll
                for (int msk = 1; msk < 16; msk <<= 1)
                    tmax[q] = fmaxf(tmax[q], __shfl_xor(tmax[q], msk));
                float mn = fmaxf(mreg[q], tmax[q]);
                float al = exp2f(mreg[q] - mn);
                mreg[q] = mn;
                #pragma unroll
                for (int jd = 0; jd < 5; jd++) o[jd][q] *= al;
            }
        }
        #pragma unroll
        for (int j = 0; j < 4; j++)
            #pragma unroll
            for (int q = 0; q < 4; q++)
                Ps[wid][lg * 4 + q][j * 16 + lr] = f2b(exp2f(sf[j][q] - mreg[q]));

        __builtin_amdgcn_s_setprio(1);
        #pragma unroll
        for (int ks = 0; ks < 2; ++ks) {
            s16x8 ap = *(const s16x8*)&Ps[wid][lr][ks * 32 + lg * 8];
            #pragma unroll
            for (int jd = 0; jd < 5; jd++) {
                s16x8 bv = *(const s16x8*)&Vt[jd * 16 + lr][ks * 32 + lg * 8];
                o[jd] = MFMA16(ap, bv, o[jd]);
            }
        }
        __builtin_amdgcn_s_setprio(0);
        __syncthreads();
    }

    short* cb = Ctx + ((long)b * T + t0) * E + h * 64;
    #pragma unroll
    for (int q = 0; q < 4; q++) {
        float s = __shfl(o[4][q], lane & 48);
        int t = wid * 16 + lg * 4 + q;
        if (t0 + t >= T) continue;
        float inv = 1.f / s;
        #pragma unroll
        for (int jd = 0; jd < 4; jd++)
            cb[(long)t * E + jd * 16 + lr] = f2b(o[jd][q] * inv);
    }
}

extern "C" void kernel_launch(void* const* d_in, const int* in_sizes, int n_in,
                              void* d_out, int out_size, void* d_ws, size_t ws_size,
                              hipStream_t stream) {
    (void)in_sizes; (void)n_in; (void)out_size; (void)ws_size;
    const int B = 16, T = 577, E = 1024, H = 16;
    const int SP = 640, TP = 640;
    const float* hs   = (const float*)d_in[0];
    const float* size = (const float*)d_in[1];
    const float* wq   = (const float*)d_in[2];
    const float* bq   = (const float*)d_in[3];
    const float* wk   = (const float*)d_in[4];
    const float* bk   = (const float*)d_in[5];
    const float* wv   = (const float*)d_in[6];
    const float* bv   = (const float*)d_in[7];
    const float* wo   = (const float*)d_in[8];
    const float* bo   = (const float*)d_in[9];

    float* out_attn = (float*)d_out;                  // B*T*E
    float* out_mk   = out_attn + (long)B * T * E;     // B*T*D
    float* out_as   = out_mk + (long)B * T * 64;      // T*T

    long nBTE = (long)B * T * E;
    long nEE  = (long)E * E;
    char* ws = (char*)d_ws;
    short* hs_b  = (short*)ws; ws += nBTE * 2;
    short* wq_b  = (short*)ws; ws += nEE * 2;   // wq|wk|wv|wo contiguous
    short* wk_b  = (short*)ws; ws += nEE * 2;
    short* wv_b  = (short*)ws; ws += nEE * 2;
    short* wo_b  = (short*)ws; ws += nEE * 2;
    short* q_b   = (short*)ws; ws += nBTE * 2;
    short* k_b   = (short*)ws; ws += nBTE * 2;
    short* v_b   = (short*)ws; ws += nBTE * 2;
    short* ctx_b = (short*)ws; ws += nBTE * 2;
    float* szpad = (float*)ws; ws += (long)B * SP * 4;
    float* att_p = (float*)ws; ws += (long)B * T * T * 4;
    short* vt = (short*)att_p;   // aliases att_p, written after reduce consumed it

    k_f32_to_bf16<<<2048, 256, 0, stream>>>(hs, hs_b, nBTE);
    {
        dim3 gw((nEE / 4 + 255) / 256, 4);
        k_wconv4<<<gw, 256, 0, stream>>>(wq, wk, wv, wo, wq_b, nEE);
    }
    k_sizepad<<<(B * SP + 255) / 256, 256, 0, stream>>>(size, szpad, B, T, SP);

    int M = B * T;  // 9232
    // fused QKV: 8-wave 64-VGPR core (occupancy 2x)
    {
        int Mtiles = (M + 127) / 128, Ntiles = 3072 / 128;   // 73 x 24 = 1752 blocks
        k_gemm8w<true><<<Mtiles * Ntiles, 512, 0, stream>>>(
            hs_b, wq_b, bq, bk, bv, q_b, k_b, v_b, nullptr, M, 3072, E, Ntiles,
            0.18033688011112042f);  // 0.125 * log2(e)
    }

    dim3 g_att((T + 127) / 128, (T + 127) / 128, B);
    k_att<<<g_att, dim3(256), 0, stream>>>(q_b, k_b, att_p, T, E);
    k_att_reduce<<<((T * T) + 255) / 256, 256, 0, stream>>>(att_p, out_as, T * T, B, (long)T * T);

    dim3 g_vt((T + 63) / 64, H, B);
    k_vtrans<<<g_vt, dim3(256), 0, stream>>>(v_b, vt, szpad, B, T, H, TP, SP);

    k_mean_keys8<<<((B * T * 8) + 255) / 256, 256, 0, stream>>>(k_b, out_mk, B * T);

    const int NTQ = (T + 63) / 64;   // 10 -> 2560 blocks (%8==0)
    int nfl = NTQ * H * B;
    k_flash<<<nfl, dim3(256), 0, stream>>>(q_b, k_b, vt, szpad, ctx_b, B, T, E, H, SP, TP, NTQ);

    {
        int Mtiles = (M + 127) / 128, Ntiles = 1024 / 128;   // 73 x 8 = 584 blocks
        k_proj32<<<Mtiles * Ntiles, 256, 0, stream>>>(
            ctx_b, wo_b, bo, out_attn, M, 1024, E, Ntiles);
    }
}

// Round 20
// 264.522 us; speedup vs baseline: 1.1003x; 1.0395x over previous
//
#include <hip/hip_runtime.h>
#include <hip/hip_bf16.h>
#include <math.h>

typedef __attribute__((ext_vector_type(8))) short s16x8;
typedef __attribute__((ext_vector_type(4))) short s16x4;
typedef __attribute__((ext_vector_type(4))) float f32x4;
typedef __attribute__((ext_vector_type(8))) __bf16 bf16x8;

#define MFMA16(a, b, c) __builtin_amdgcn_mfma_f32_16x16x32_bf16( \
    __builtin_bit_cast(bf16x8, (a)), __builtin_bit_cast(bf16x8, (b)), (c), 0, 0, 0)

__device__ __forceinline__ short f2b(float f) {
    __bf16 h = (__bf16)f;
    return __builtin_bit_cast(short, h);
}
__device__ __forceinline__ float b2f(short b) {
    union { unsigned u; float f; } x;
    x.u = ((unsigned)(unsigned short)b) << 16;
    return x.f;
}

__device__ __forceinline__ void gload16(const void* g, void* l) {
    __builtin_amdgcn_global_load_lds(
        (const __attribute__((address_space(1))) unsigned int*)g,
        (__attribute__((address_space(3))) unsigned int*)l, 16, 0, 0);
}

// ---------------- fp32 -> bf16 convert (hidden states) ----------------
__global__ void k_f32_to_bf16(const float* __restrict__ in, short* __restrict__ out, long n) {
    long i = ((long)blockIdx.x * blockDim.x + threadIdx.x) * 4;
    long stride = (long)gridDim.x * blockDim.x * 4;
    for (; i < n; i += stride) {
        float4 v = *(const float4*)(in + i);
        s16x4 o = { f2b(v.x), f2b(v.y), f2b(v.z), f2b(v.w) };
        *(s16x4*)(out + i) = o;
    }
}

// ---------------- fused 4-weight convert ----------------
__global__ void k_wconv4(const float* __restrict__ w0, const float* __restrict__ w1,
                         const float* __restrict__ w2, const float* __restrict__ w3,
                         short* __restrict__ out, long n) {
    int wsel = blockIdx.y;
    const float* src = (wsel == 0) ? w0 : (wsel == 1) ? w1 : (wsel == 2) ? w2 : w3;
    short* dst = out + (long)wsel * n;
    long i = ((long)blockIdx.x * blockDim.x + threadIdx.x) * 4;
    if (i >= n) return;
    float4 v = *(const float4*)(src + i);
    s16x4 o = { f2b(v.x), f2b(v.y), f2b(v.z), f2b(v.w) };
    *(s16x4*)(dst + i) = o;
}

// ---------------- raw size with 0-padding ----------------
__global__ void k_sizepad(const float* __restrict__ size, float* __restrict__ out,
                          int B, int T, int SP) {
    int i = blockIdx.x * blockDim.x + threadIdx.x;
    if (i >= B * SP) return;
    int b = i / SP, s = i % SP;
    out[i] = (s < T) ? size[b * T + s] : 0.f;
}

// ======== QKV: 128x128 tile, 8 waves x (32x64), BK=64, 32KB LDS, 64-VGPR (r19 winner) ========
template<bool ROUTE>
__global__ __launch_bounds__(512, 4) void k_gemm8w(
    const short* __restrict__ A, const short* __restrict__ Bw,
    const float* __restrict__ bb0, const float* __restrict__ bb1, const float* __restrict__ bb2,
    short* __restrict__ o0, short* __restrict__ o1, short* __restrict__ o2,
    float* __restrict__ Cf, int M, int N, int K, int Ntiles, float alpha0) {

    __shared__ short As[128 * 64];
    __shared__ short Bs[128 * 64];

    int nwg = gridDim.x, orig = blockIdx.x;
    int qq = nwg >> 3, rr = nwg & 7;
    int xcd = orig & 7, pos = orig >> 3;
    int wg = (xcd < rr ? xcd * (qq + 1) : rr * (qq + 1) + (xcd - rr) * qq) + pos;
    int bx = wg % Ntiles, by = wg / Ntiles;
    int row0 = by * 128, col0 = bx * 128;

    int tid = threadIdx.x;
    int lane = tid & 63, wave = tid >> 6;
    int wr = wave >> 1, wc = wave & 1;
    int lr = lane & 15, lg = lane >> 4;

    f32x4 acc[2][4];
    #pragma unroll
    for (int i = 0; i < 2; i++)
        #pragma unroll
        for (int j = 0; j < 4; j++)
            #pragma unroll
            for (int q = 0; q < 4; q++) acc[i][j][q] = 0.f;

    for (int k0 = 0; k0 < K; k0 += 64) {
        __syncthreads();
        #pragma unroll
        for (int jj = 0; jj < 2; ++jj) {
            int ch = tid + jj * 512;
            int r = ch >> 3;
            int cby = ((ch & 7) * 16) ^ ((r & 7) << 4);
            int ra = row0 + r; ra = ra < M ? ra : M - 1;
            gload16((const char*)(A + (long)ra * K + k0) + cby, &As[ch * 8]);
            int rb = col0 + r; rb = rb < N ? rb : N - 1;
            gload16((const char*)(Bw + (long)rb * K + k0) + cby, &Bs[ch * 8]);
        }
        __syncthreads();
        #pragma unroll
        for (int ks = 0; ks < 2; ++ks) {
            s16x8 af[2];
            #pragma unroll
            for (int i = 0; i < 2; ++i) {
                int r = wr * 32 + i * 16 + lr;
                af[i] = *(const s16x8*)((const char*)As + r * 128 +
                        (((ks << 6) + (lg << 4)) ^ ((r & 7) << 4)));
            }
            #pragma unroll
            for (int j = 0; j < 4; ++j) {
                int r = wc * 64 + j * 16 + lr;
                s16x8 bfr = *(const s16x8*)((const char*)Bs + r * 128 +
                            (((ks << 6) + (lg << 4)) ^ ((r & 7) << 4)));
                acc[0][j] = MFMA16(af[0], bfr, acc[0][j]);
                acc[1][j] = MFMA16(af[1], bfr, acc[1][j]);
            }
        }
    }

    #pragma unroll
    for (int i = 0; i < 2; i++) {
        int grow0 = row0 + wr * 32 + i * 16 + lg * 4;
        #pragma unroll
        for (int j = 0; j < 4; j++) {
            int gc = col0 + wc * 64 + j * 16 + lr;
            if (gc >= N) continue;
            if (ROUTE) {
                int which = gc >> 10, lc = gc & 1023;
                float bias = (which == 0 ? bb0 : which == 1 ? bb1 : bb2)[lc];
                float alpha = (which == 0) ? alpha0 : 1.0f;
                short* op = (which == 0 ? o0 : which == 1 ? o1 : o2);
                #pragma unroll
                for (int q = 0; q < 4; ++q) {
                    int r2 = grow0 + q;
                    if (r2 < M) op[(long)r2 * 1024 + lc] = f2b((acc[i][j][q] + bias) * alpha);
                }
            } else {
                float bias = bb0[gc];
                #pragma unroll
                for (int q = 0; q < 4; ++q) {
                    int r2 = grow0 + q;
                    if (r2 < M) Cf[(long)r2 * N + gc] = acc[i][j][q] + bias;
                }
            }
        }
    }
}

// ======== latency-hiding core: BK=32, 2-deep dbuf in 32KB LDS (att/proj) ====
__device__ __forceinline__ void core32(
    const short* __restrict__ A, const short* __restrict__ Bw,
    int M, int N, int K, int row0, int col0,
    short* AS, short* BS,
    f32x4 acc[4][4]) {
    int tid = threadIdx.x;
    int lane = tid & 63, wave = tid >> 6;
    int wr = wave >> 1, wc = wave & 1;
    int lr = lane & 15, lg = lane >> 4;

    const char* ga[2]; const char* gb[2]; int ldo[2];
    #pragma unroll
    for (int j = 0; j < 2; ++j) {
        int ch = j * 256 + wave * 64 + lane;
        int r = ch >> 2, slot = ch & 3;
        int cby = (slot << 4) ^ (((r >> 1) & 3) << 4);
        int ra = row0 + r; ra = ra < M ? ra : M - 1;
        int rb = col0 + r; rb = rb < N ? rb : N - 1;
        ga[j] = (const char*)(A + (long)ra * K) + cby;
        gb[j] = (const char*)(Bw + (long)rb * K) + cby;
        ldo[j] = ch * 8;
    }
    #pragma unroll
    for (int i = 0; i < 4; i++)
        #pragma unroll
        for (int j = 0; j < 4; j++)
            #pragma unroll
            for (int q = 0; q < 4; q++) acc[i][j][q] = 0.f;

    #pragma unroll
    for (int j = 0; j < 2; ++j) {
        gload16(ga[j], AS + ldo[j]);
        gload16(gb[j], BS + ldo[j]);
        ga[j] += 64; gb[j] += 64;
    }

    int nt = K >> 5;
    for (int t = 0; t < nt; ++t) {
        int cur = t & 1;
        asm volatile("s_waitcnt vmcnt(0)" ::: "memory");
        __builtin_amdgcn_s_barrier();
        if (t + 1 < nt) {
            short* Ad = AS + (cur ^ 1) * 4096;
            short* Bd = BS + (cur ^ 1) * 4096;
            #pragma unroll
            for (int j = 0; j < 2; ++j) {
                gload16(ga[j], Ad + ldo[j]);
                gload16(gb[j], Bd + ldo[j]);
                ga[j] += 64; gb[j] += 64;
            }
        }
        const short* Ab2 = AS + cur * 4096;
        const short* Bb2 = BS + cur * 4096;
        s16x8 af[4], bfr[4];
        #pragma unroll
        for (int i = 0; i < 4; ++i) {
            int r = wr * 64 + i * 16 + lr;
            af[i] = *(const s16x8*)((const char*)Ab2 + r * 64 +
                    ((lg << 4) ^ (((r >> 1) & 3) << 4)));
        }
        #pragma unroll
        for (int j = 0; j < 4; ++j) {
            int r = wc * 64 + j * 16 + lr;
            bfr[j] = *(const s16x8*)((const char*)Bb2 + r * 64 +
                     ((lg << 4) ^ (((r >> 1) & 3) << 4)));
        }
        __builtin_amdgcn_s_setprio(1);
        #pragma unroll
        for (int i = 0; i < 4; ++i)
            #pragma unroll
            for (int j = 0; j < 4; ++j)
                acc[i][j] = MFMA16(af[i], bfr[j], acc[i][j]);
        __builtin_amdgcn_s_setprio(0);
    }
}

// proj on core32 (fp32 epilogue + bias)
__global__ __launch_bounds__(256) void k_proj32(
    const short* __restrict__ A, const short* __restrict__ Bw,
    const float* __restrict__ bias, float* __restrict__ Cf,
    int M, int N, int K, int Ntiles) {
    __shared__ short AS[2][128 * 32];
    __shared__ short BS[2][128 * 32];

    int nwg = gridDim.x, orig = blockIdx.x;
    int qq = nwg >> 3, rr = nwg & 7;
    int xcd = orig & 7, pos = orig >> 3;
    int wg = (xcd < rr ? xcd * (qq + 1) : rr * (qq + 1) + (xcd - rr) * qq) + pos;
    int bx = wg % Ntiles, by = wg / Ntiles;
    int row0 = by * 128, col0 = bx * 128;

    int tid = threadIdx.x;
    int lane = tid & 63, wave = tid >> 6;
    int wr = wave >> 1, wc = wave & 1;
    int lr = lane & 15, lg = lane >> 4;

    f32x4 acc[4][4];
    core32(A, Bw, M, N, K, row0, col0, &AS[0][0], &BS[0][0], acc);

    #pragma unroll
    for (int i = 0; i < 4; i++) {
        int grow0 = row0 + wr * 64 + i * 16 + lg * 4;
        #pragma unroll
        for (int j = 0; j < 4; j++) {
            int gc = col0 + wc * 64 + j * 16 + lr;
            if (gc >= N) continue;
            float bv = bias[gc];
            #pragma unroll
            for (int q = 0; q < 4; ++q) {
                int r2 = grow0 + q;
                if (r2 < M) Cf[(long)r2 * N + gc] = acc[i][j][q] + bv;
            }
        }
    }
}

// ---------------- att partials: core32, fp32 epilogue ----------------
__global__ __launch_bounds__(256) void k_att(
    const short* __restrict__ q, const short* __restrict__ k,
    float* __restrict__ attp, int T, int E) {
    __shared__ short AS[2][128 * 32];
    __shared__ short BS[2][128 * 32];
    int z = blockIdx.z;
    const short* Ab = q + (long)z * T * E;
    const short* Bb = k + (long)z * T * E;
    float* Cf = attp + (long)z * T * T;
    int row0 = blockIdx.y * 128, col0 = blockIdx.x * 128;

    int tid = threadIdx.x;
    int lane = tid & 63, wave = tid >> 6;
    int wr = wave >> 1, wc = wave & 1;
    int lr = lane & 15, lg = lane >> 4;

    f32x4 acc[4][4];
    core32(Ab, Bb, T, T, E, row0, col0, &AS[0][0], &BS[0][0], acc);

    #pragma unroll
    for (int i = 0; i < 4; i++) {
        int rbase = row0 + wr * 64 + i * 16 + lg * 4;
        #pragma unroll
        for (int j = 0; j < 4; j++) {
            int c = col0 + wc * 64 + j * 16 + lr;
            if (c >= T) continue;
            #pragma unroll
            for (int q2 = 0; q2 < 4; q2++) {
                int r = rbase + q2;
                if (r >= T) continue;
                Cf[(long)r * T + c] = acc[i][j][q2];
            }
        }
    }
}

// ---------------- mean over heads of K ----------------
__global__ void k_mean_keys8(const short* __restrict__ Kb, float* __restrict__ out, int BT) {
    int i = blockIdx.x * blockDim.x + threadIdx.x;
    if (i >= BT * 8) return;
    int bt = i >> 3, d0 = (i & 7) * 8;
    const short* p = Kb + (long)bt * 1024 + d0;
    float s[8] = {0.f, 0.f, 0.f, 0.f, 0.f, 0.f, 0.f, 0.f};
    #pragma unroll
    for (int h = 0; h < 16; ++h) {
        s16x8 v = *(const s16x8*)(p + h * 64);
        #pragma unroll
        for (int j = 0; j < 8; ++j) s[j] += b2f(v[j]);
    }
    float4 o0 = {s[0] * 0.0625f, s[1] * 0.0625f, s[2] * 0.0625f, s[3] * 0.0625f};
    float4 o1 = {s[4] * 0.0625f, s[5] * 0.0625f, s[6] * 0.0625f, s[7] * 0.0625f};
    *(float4*)(out + (long)bt * 64 + d0) = o0;
    *(float4*)(out + (long)bt * 64 + d0 + 4) = o1;
}

// ---------------- reduce att_score partials over batch ----------------
__global__ void k_att_reduce(const float* __restrict__ part, float* __restrict__ out,
                             int n, int nb, long stride) {
    int i = blockIdx.x * blockDim.x + threadIdx.x;
    if (i >= n) return;
    float s = 0.f;
    for (int b = 0; b < nb; ++b) s += part[(long)b * stride + i];
    out[i] = s * 0.002707606174062286f;  // ln(2)/256 compensates log2e folded into q
}

// ---------------- V transpose + size pre-scale ----------------
__global__ __launch_bounds__(256) void k_vtrans(const short* __restrict__ v, short* __restrict__ vt,
                                                const float* __restrict__ szp,
                                                int B, int T, int H, int TP, int SP) {
    int b = blockIdx.z, h = blockIdx.y, t0 = blockIdx.x * 64;
    __shared__ short Vs[64][68];
    __shared__ float Szs[64];
    int tid = threadIdx.x;
    if (tid < 64) Szs[tid] = szp[b * SP + t0 + tid];
    for (int c = tid; c < 512; c += 256) {
        int r = c >> 3, m = c & 7;
        s16x8 val = {0,0,0,0,0,0,0,0};
        if (t0 + r < T) val = *(const s16x8*)(v + ((long)(b * T + t0 + r)) * (H * 64) + h * 64 + m * 8);
        *(s16x8*)&Vs[r][m * 8] = val;
    }
    __syncthreads();
    for (int c = tid; c < 512; c += 256) {
        int d = c >> 3, mw = c & 7;
        s16x8 o;
        #pragma unroll
        for (int j = 0; j < 8; j++) o[j] = f2b(b2f(Vs[mw * 8 + j][d]) * Szs[mw * 8 + j]);
        *(s16x8*)(vt + ((long)((b * H + h) * 64 + d)) * TP + t0 + mw * 8) = o;
    }
}

// ---------------- flash attention v7: gload_lds K/V staging (swizzled), low-VGPR ----------------
// LDS: KsL [64][64] swizzled; VtL [80][64] swizzled (row 64 = size, rows 65-79 zero).
__global__ __launch_bounds__(256) void k_flash(
    const short* __restrict__ Q, const short* __restrict__ Kb, const short* __restrict__ VT,
    const float* __restrict__ szp, short* __restrict__ Ctx,
    int B, int T, int E, int H, int SP, int TP, int NTQ) {
    int nwg = gridDim.x;
    int cpx = nwg >> 3;
    int wg = (blockIdx.x & 7) * cpx + (blockIdx.x >> 3);
    int tq = wg % NTQ, h = (wg / NTQ) % H, b = wg / (NTQ * H);
    int t0 = tq * 64;

    __shared__ short KsL[64 * 64];
    __shared__ short VtL[80 * 64];
    __shared__ short Ps[4][16][68];
    int tid = threadIdx.x, wid = tid >> 6, lane = tid & 63;
    int lr = lane & 15, lg = lane >> 4;

    // zero rows 65..79 once (reads XOR within zeroed region -> still zero)
    for (int c = tid; c < 15 * 64; c += 256) VtL[65 * 64 + c] = 0;

    s16x8 aqf[2];
    {
        int t = t0 + wid * 16 + lr; t = t < T ? t : T - 1;
        #pragma unroll
        for (int ks = 0; ks < 2; ++ks)
            aqf[ks] = *(const s16x8*)(Q + ((long)b * T + t) * E + h * 64 + ks * 32 + lg * 8);
    }

    const short* kb  = Kb + (long)b * T * E + h * 64;
    const short* vtb = VT + ((long)(b * H + h)) * 64 * TP;

    // hoisted staging geometry: 512 chunks each for K and V, 2 per thread
    int ch0 = tid, ch1 = tid + 256;
    int kr0 = ch0 >> 3, kc0 = ((ch0 & 7) * 16) ^ ((kr0 & 7) << 4);
    int kr1 = ch1 >> 3, kc1 = ((ch1 & 7) * 16) ^ ((kr1 & 7) << 4);

    float szreg = (tid < 64) ? szp[b * SP + tid] : 0.f;

    float mreg[4];
    f32x4 o[5];
    #pragma unroll
    for (int q = 0; q < 4; q++) mreg[q] = -INFINITY;
    #pragma unroll
    for (int jd = 0; jd < 5; jd++)
        #pragma unroll
        for (int q = 0; q < 4; q++) o[jd][q] = 0.f;

    for (int s0 = 0; s0 < T; s0 += 64) {
        __syncthreads();   // prior tile's LDS reads complete (and init writes, first iter)
        // async stage K rows (clamped) and V'^T rows into swizzled-linear LDS
        {
            int s = s0 + kr0; s = s < T ? s : T - 1;
            gload16((const char*)(kb + (long)s * E) + kc0, &KsL[ch0 * 8]);
            s = s0 + kr1; s = s < T ? s : T - 1;
            gload16((const char*)(kb + (long)s * E) + kc1, &KsL[ch1 * 8]);
            gload16((const char*)(vtb + (long)kr0 * TP + s0) + kc0, &VtL[ch0 * 8]);
            gload16((const char*)(vtb + (long)kr1 * TP + s0) + kc1, &VtL[ch1 * 8]);
        }
        if (tid < 64) {
            VtL[64 * 64 + tid] = f2b(szreg);              // row 64: (64&7)=0 -> linear
            if (s0 + 64 < T) szreg = szp[b * SP + s0 + 64 + tid];
        }
        asm volatile("s_waitcnt vmcnt(0)" ::: "memory");
        __syncthreads();

        f32x4 sf[4];
        #pragma unroll
        for (int j = 0; j < 4; j++)
            #pragma unroll
            for (int q = 0; q < 4; q++) sf[j][q] = 0.f;
        __builtin_amdgcn_s_setprio(1);
        #pragma unroll
        for (int ks = 0; ks < 2; ++ks)
            #pragma unroll
            for (int j = 0; j < 4; j++) {
                int r = j * 16 + lr;
                s16x8 bk = *(const s16x8*)((const char*)KsL + r * 128 +
                           (((ks << 6) + (lg << 4)) ^ ((r & 7) << 4)));
                sf[j] = MFMA16(aqf[ks], bk, sf[j]);
            }
        __builtin_amdgcn_s_setprio(0);

        float tmax[4];
        #pragma unroll
        for (int q = 0; q < 4; q++)
            tmax[q] = fmaxf(fmaxf(sf[0][q], sf[1][q]), fmaxf(sf[2][q], sf[3][q]));
        int ok = 1;
        #pragma unroll
        for (int q = 0; q < 4; q++) ok &= (tmax[q] <= mreg[q] + 11.0f) ? 1 : 0;
        if (!__all(ok)) {
            #pragma unroll
            for (int q = 0; q < 4; q++) {
                #pragma unroll
                for (int msk = 1; msk < 16; msk <<= 1)
                    tmax[q] = fmaxf(tmax[q], __shfl_xor(tmax[q], msk));
                float mn = fmaxf(mreg[q], tmax[q]);
                float al = exp2f(mreg[q] - mn);
                mreg[q] = mn;
                #pragma unroll
                for (int jd = 0; jd < 5; jd++) o[jd][q] *= al;
            }
        }
        #pragma unroll
        for (int j = 0; j < 4; j++)
            #pragma unroll
            for (int q = 0; q < 4; q++)
                Ps[wid][lg * 4 + q][j * 16 + lr] = f2b(exp2f(sf[j][q] - mreg[q]));

        __builtin_amdgcn_s_setprio(1);
        #pragma unroll
        for (int ks = 0; ks < 2; ++ks) {
            s16x8 ap = *(const s16x8*)&Ps[wid][lr][ks * 32 + lg * 8];
            #pragma unroll
            for (int jd = 0; jd < 5; jd++) {
                int r = jd * 16 + lr;
                s16x8 bv = *(const s16x8*)((const char*)VtL + r * 128 +
                           (((ks << 6) + (lg << 4)) ^ ((r & 7) << 4)));
                o[jd] = MFMA16(ap, bv, o[jd]);
            }
        }
        __builtin_amdgcn_s_setprio(0);
    }

    short* cb = Ctx + ((long)b * T + t0) * E + h * 64;
    #pragma unroll
    for (int q = 0; q < 4; q++) {
        float s = __shfl(o[4][q], lane & 48);
        int t = wid * 16 + lg * 4 + q;
        if (t0 + t >= T) continue;
        float inv = 1.f / s;
        #pragma unroll
        for (int jd = 0; jd < 4; jd++)
            cb[(long)t * E + jd * 16 + lr] = f2b(o[jd][q] * inv);
    }
}

extern "C" void kernel_launch(void* const* d_in, const int* in_sizes, int n_in,
                              void* d_out, int out_size, void* d_ws, size_t ws_size,
                              hipStream_t stream) {
    (void)in_sizes; (void)n_in; (void)out_size; (void)ws_size;
    const int B = 16, T = 577, E = 1024, H = 16;
    const int SP = 640, TP = 640;
    const float* hs   = (const float*)d_in[0];
    const float* size = (const float*)d_in[1];
    const float* wq   = (const float*)d_in[2];
    const float* bq   = (const float*)d_in[3];
    const float* wk   = (const float*)d_in[4];
    const float* bk   = (const float*)d_in[5];
    const float* wv   = (const float*)d_in[6];
    const float* bv   = (const float*)d_in[7];
    const float* wo   = (const float*)d_in[8];
    const float* bo   = (const float*)d_in[9];

    float* out_attn = (float*)d_out;                  // B*T*E
    float* out_mk   = out_attn + (long)B * T * E;     // B*T*D
    float* out_as   = out_mk + (long)B * T * 64;      // T*T

    long nBTE = (long)B * T * E;
    long nEE  = (long)E * E;
    char* ws = (char*)d_ws;
    short* hs_b  = (short*)ws; ws += nBTE * 2;
    short* wq_b  = (short*)ws; ws += nEE * 2;   // wq|wk|wv|wo contiguous
    short* wk_b  = (short*)ws; ws += nEE * 2;
    short* wv_b  = (short*)ws; ws += nEE * 2;
    short* wo_b  = (short*)ws; ws += nEE * 2;
    short* q_b   = (short*)ws; ws += nBTE * 2;
    short* k_b   = (short*)ws; ws += nBTE * 2;
    short* v_b   = (short*)ws; ws += nBTE * 2;
    short* ctx_b = (short*)ws; ws += nBTE * 2;
    float* szpad = (float*)ws; ws += (long)B * SP * 4;
    float* att_p = (float*)ws; ws += (long)B * T * T * 4;
    short* vt = (short*)att_p;   // aliases att_p, written after reduce consumed it

    k_f32_to_bf16<<<2048, 256, 0, stream>>>(hs, hs_b, nBTE);
    {
        dim3 gw((nEE / 4 + 255) / 256, 4);
        k_wconv4<<<gw, 256, 0, stream>>>(wq, wk, wv, wo, wq_b, nEE);
    }
    k_sizepad<<<(B * SP + 255) / 256, 256, 0, stream>>>(size, szpad, B, T, SP);

    int M = B * T;  // 9232
    {
        int Mtiles = (M + 127) / 128, Ntiles = 3072 / 128;   // 73 x 24 = 1752 blocks
        k_gemm8w<true><<<Mtiles * Ntiles, 512, 0, stream>>>(
            hs_b, wq_b, bq, bk, bv, q_b, k_b, v_b, nullptr, M, 3072, E, Ntiles,
            0.18033688011112042f);  // 0.125 * log2(e)
    }

    dim3 g_att((T + 127) / 128, (T + 127) / 128, B);
    k_att<<<g_att, dim3(256), 0, stream>>>(q_b, k_b, att_p, T, E);
    k_att_reduce<<<((T * T) + 255) / 256, 256, 0, stream>>>(att_p, out_as, T * T, B, (long)T * T);

    dim3 g_vt((T + 63) / 64, H, B);
    k_vtrans<<<g_vt, dim3(256), 0, stream>>>(v_b, vt, szpad, B, T, H, TP, SP);

    k_mean_keys8<<<((B * T * 8) + 255) / 256, 256, 0, stream>>>(k_b, out_mk, B * T);

    const int NTQ = (T + 63) / 64;   // 10 -> 2560 blocks (%8==0)
    int nfl = NTQ * H * B;
    k_flash<<<nfl, dim3(256), 0, stream>>>(q_b, k_b, vt, szpad, ctx_b, B, T, E, H, SP, TP, NTQ);

    {
        int Mtiles = (M + 127) / 128, Ntiles = 1024 / 128;   // 73 x 8 = 584 blocks
        k_proj32<<<Mtiles * Ntiles, 256, 0, stream>>>(
            ctx_b, wo_b, bo, out_attn, M, 1024, E, Ntiles);
    }
}

// Round 21
// 248.177 us; speedup vs baseline: 1.1728x; 1.0659x over previous
//
#include <hip/hip_runtime.h>
#include <hip/hip_bf16.h>
#include <math.h>

typedef __attribute__((ext_vector_type(8))) short s16x8;
typedef __attribute__((ext_vector_type(4))) short s16x4;
typedef __attribute__((ext_vector_type(4))) float f32x4;
typedef __attribute__((ext_vector_type(8))) __bf16 bf16x8;

#define MFMA16(a, b, c) __builtin_amdgcn_mfma_f32_16x16x32_bf16( \
    __builtin_bit_cast(bf16x8, (a)), __builtin_bit_cast(bf16x8, (b)), (c), 0, 0, 0)

__device__ __forceinline__ short f2b(float f) {
    __bf16 h = (__bf16)f;
    return __builtin_bit_cast(short, h);
}
__device__ __forceinline__ float b2f(short b) {
    union { unsigned u; float f; } x;
    x.u = ((unsigned)(unsigned short)b) << 16;
    return x.f;
}

__device__ __forceinline__ void gload16(const void* g, void* l) {
    __builtin_amdgcn_global_load_lds(
        (const __attribute__((address_space(1))) unsigned int*)g,
        (__attribute__((address_space(3))) unsigned int*)l, 16, 0, 0);
}

// ---------------- fp32 -> bf16 convert (hidden states) ----------------
__global__ void k_f32_to_bf16(const float* __restrict__ in, short* __restrict__ out, long n) {
    long i = ((long)blockIdx.x * blockDim.x + threadIdx.x) * 4;
    long stride = (long)gridDim.x * blockDim.x * 4;
    for (; i < n; i += stride) {
        float4 v = *(const float4*)(in + i);
        s16x4 o = { f2b(v.x), f2b(v.y), f2b(v.z), f2b(v.w) };
        *(s16x4*)(out + i) = o;
    }
}

// ---------------- fused 4-weight convert ----------------
__global__ void k_wconv4(const float* __restrict__ w0, const float* __restrict__ w1,
                         const float* __restrict__ w2, const float* __restrict__ w3,
                         short* __restrict__ out, long n) {
    int wsel = blockIdx.y;
    const float* src = (wsel == 0) ? w0 : (wsel == 1) ? w1 : (wsel == 2) ? w2 : w3;
    short* dst = out + (long)wsel * n;
    long i = ((long)blockIdx.x * blockDim.x + threadIdx.x) * 4;
    if (i >= n) return;
    float4 v = *(const float4*)(src + i);
    s16x4 o = { f2b(v.x), f2b(v.y), f2b(v.z), f2b(v.w) };
    *(s16x4*)(dst + i) = o;
}

// ---------------- raw size with 0-padding ----------------
__global__ void k_sizepad(const float* __restrict__ size, float* __restrict__ out,
                          int B, int T, int SP) {
    int i = blockIdx.x * blockDim.x + threadIdx.x;
    if (i >= B * SP) return;
    int b = i / SP, s = i % SP;
    out[i] = (s < T) ? size[b * T + s] : 0.f;
}

// ======== shared 8-wave core: 128x128 tile, 8 waves x (32x64), BK=64, 32KB LDS ========
// VGPR ~36 (r20 measured) -> high occupancy; swizzle HW-validated.
__device__ __forceinline__ void core8w(
    const short* __restrict__ A, const short* __restrict__ Bw,
    int M, int N, int K, int row0, int col0,
    short* As, short* Bs, f32x4 acc[2][4]) {
    int tid = threadIdx.x;
    int lane = tid & 63, wave = tid >> 6;
    int wr = wave >> 1, wc = wave & 1;
    int lr = lane & 15, lg = lane >> 4;

    #pragma unroll
    for (int i = 0; i < 2; i++)
        #pragma unroll
        for (int j = 0; j < 4; j++)
            #pragma unroll
            for (int q = 0; q < 4; q++) acc[i][j][q] = 0.f;

    for (int k0 = 0; k0 < K; k0 += 64) {
        __syncthreads();
        #pragma unroll
        for (int jj = 0; jj < 2; ++jj) {
            int ch = tid + jj * 512;
            int r = ch >> 3;
            int cby = ((ch & 7) * 16) ^ ((r & 7) << 4);
            int ra = row0 + r; ra = ra < M ? ra : M - 1;
            gload16((const char*)(A + (long)ra * K + k0) + cby, &As[ch * 8]);
            int rb = col0 + r; rb = rb < N ? rb : N - 1;
            gload16((const char*)(Bw + (long)rb * K + k0) + cby, &Bs[ch * 8]);
        }
        __syncthreads();
        #pragma unroll
        for (int ks = 0; ks < 2; ++ks) {
            s16x8 af[2];
            #pragma unroll
            for (int i = 0; i < 2; ++i) {
                int r = wr * 32 + i * 16 + lr;
                af[i] = *(const s16x8*)((const char*)As + r * 128 +
                        (((ks << 6) + (lg << 4)) ^ ((r & 7) << 4)));
            }
            #pragma unroll
            for (int j = 0; j < 4; ++j) {
                int r = wc * 64 + j * 16 + lr;
                s16x8 bfr = *(const s16x8*)((const char*)Bs + r * 128 +
                            (((ks << 6) + (lg << 4)) ^ ((r & 7) << 4)));
                acc[0][j] = MFMA16(af[0], bfr, acc[0][j]);
                acc[1][j] = MFMA16(af[1], bfr, acc[1][j]);
            }
        }
    }
}

// QKV: routed bf16 epilogue
template<bool ROUTE>
__global__ __launch_bounds__(512, 4) void k_gemm8w(
    const short* __restrict__ A, const short* __restrict__ Bw,
    const float* __restrict__ bb0, const float* __restrict__ bb1, const float* __restrict__ bb2,
    short* __restrict__ o0, short* __restrict__ o1, short* __restrict__ o2,
    float* __restrict__ Cf, int M, int N, int K, int Ntiles, float alpha0) {

    __shared__ short As[128 * 64];
    __shared__ short Bs[128 * 64];

    int nwg = gridDim.x, orig = blockIdx.x;
    int qq = nwg >> 3, rr = nwg & 7;
    int xcd = orig & 7, pos = orig >> 3;
    int wg = (xcd < rr ? xcd * (qq + 1) : rr * (qq + 1) + (xcd - rr) * qq) + pos;
    int bx = wg % Ntiles, by = wg / Ntiles;
    int row0 = by * 128, col0 = bx * 128;

    int tid = threadIdx.x;
    int lane = tid & 63, wave = tid >> 6;
    int wr = wave >> 1, wc = wave & 1;
    int lr = lane & 15, lg = lane >> 4;

    f32x4 acc[2][4];
    core8w(A, Bw, M, N, K, row0, col0, As, Bs, acc);

    #pragma unroll
    for (int i = 0; i < 2; i++) {
        int grow0 = row0 + wr * 32 + i * 16 + lg * 4;
        #pragma unroll
        for (int j = 0; j < 4; j++) {
            int gc = col0 + wc * 64 + j * 16 + lr;
            if (gc >= N) continue;
            if (ROUTE) {
                int which = gc >> 10, lc = gc & 1023;
                float bias = (which == 0 ? bb0 : which == 1 ? bb1 : bb2)[lc];
                float alpha = (which == 0) ? alpha0 : 1.0f;
                short* op = (which == 0 ? o0 : which == 1 ? o1 : o2);
                #pragma unroll
                for (int q = 0; q < 4; ++q) {
                    int r2 = grow0 + q;
                    if (r2 < M) op[(long)r2 * 1024 + lc] = f2b((acc[i][j][q] + bias) * alpha);
                }
            } else {
                float bias = bb0[gc];
                #pragma unroll
                for (int q = 0; q < 4; ++q) {
                    int r2 = grow0 + q;
                    if (r2 < M) Cf[(long)r2 * N + gc] = acc[i][j][q] + bias;
                }
            }
        }
    }
}

// att partials on the 8-wave core: flattened grid 400 blocks (z*25 + by*5 + bx)
__global__ __launch_bounds__(512, 4) void k_att8w(
    const short* __restrict__ q, const short* __restrict__ k,
    float* __restrict__ attp, int T, int E, int Ntiles) {
    __shared__ short As[128 * 64];
    __shared__ short Bs[128 * 64];

    int nwg = gridDim.x, orig = blockIdx.x;
    int qq = nwg >> 3, rr = nwg & 7;
    int xcd = orig & 7, pos = orig >> 3;
    int wg = (xcd < rr ? xcd * (qq + 1) : rr * (qq + 1) + (xcd - rr) * qq) + pos;
    int per = Ntiles * Ntiles;
    int z = wg / per, rem = wg % per;
    int by = rem / Ntiles, bx = rem % Ntiles;
    int row0 = by * 128, col0 = bx * 128;

    const short* Ab = q + (long)z * T * E;
    const short* Bb = k + (long)z * T * E;
    float* Cf = attp + (long)z * T * T;

    int tid = threadIdx.x;
    int lane = tid & 63, wave = tid >> 6;
    int wr = wave >> 1, wc = wave & 1;
    int lr = lane & 15, lg = lane >> 4;

    f32x4 acc[2][4];
    core8w(Ab, Bb, T, T, E, row0, col0, As, Bs, acc);

    #pragma unroll
    for (int i = 0; i < 2; i++) {
        int grow0 = row0 + wr * 32 + i * 16 + lg * 4;
        #pragma unroll
        for (int j = 0; j < 4; j++) {
            int c = col0 + wc * 64 + j * 16 + lr;
            if (c >= T) continue;
            #pragma unroll
            for (int q2 = 0; q2 < 4; q2++) {
                int r = grow0 + q2;
                if (r >= T) continue;
                Cf[(long)r * T + c] = acc[i][j][q2];
            }
        }
    }
}

// proj on the 8-wave core: fp32 + bias
__global__ __launch_bounds__(512, 4) void k_proj8w(
    const short* __restrict__ A, const short* __restrict__ Bw,
    const float* __restrict__ bias, float* __restrict__ Cf,
    int M, int N, int K, int Ntiles) {
    __shared__ short As[128 * 64];
    __shared__ short Bs[128 * 64];

    int nwg = gridDim.x, orig = blockIdx.x;
    int qq = nwg >> 3, rr = nwg & 7;
    int xcd = orig & 7, pos = orig >> 3;
    int wg = (xcd < rr ? xcd * (qq + 1) : rr * (qq + 1) + (xcd - rr) * qq) + pos;
    int bx = wg % Ntiles, by = wg / Ntiles;
    int row0 = by * 128, col0 = bx * 128;

    int tid = threadIdx.x;
    int lane = tid & 63, wave = tid >> 6;
    int wr = wave >> 1, wc = wave & 1;
    int lr = lane & 15, lg = lane >> 4;

    f32x4 acc[2][4];
    core8w(A, Bw, M, N, K, row0, col0, As, Bs, acc);

    #pragma unroll
    for (int i = 0; i < 2; i++) {
        int grow0 = row0 + wr * 32 + i * 16 + lg * 4;
        #pragma unroll
        for (int j = 0; j < 4; j++) {
            int gc = col0 + wc * 64 + j * 16 + lr;
            if (gc >= N) continue;
            float bv = bias[gc];
            #pragma unroll
            for (int q = 0; q < 4; ++q) {
                int r2 = grow0 + q;
                if (r2 < M) Cf[(long)r2 * N + gc] = acc[i][j][q] + bv;
            }
        }
    }
}

// ---------------- mean over heads of K ----------------
__global__ void k_mean_keys8(const short* __restrict__ Kb, float* __restrict__ out, int BT) {
    int i = blockIdx.x * blockDim.x + threadIdx.x;
    if (i >= BT * 8) return;
    int bt = i >> 3, d0 = (i & 7) * 8;
    const short* p = Kb + (long)bt * 1024 + d0;
    float s[8] = {0.f, 0.f, 0.f, 0.f, 0.f, 0.f, 0.f, 0.f};
    #pragma unroll
    for (int h = 0; h < 16; ++h) {
        s16x8 v = *(const s16x8*)(p + h * 64);
        #pragma unroll
        for (int j = 0; j < 8; ++j) s[j] += b2f(v[j]);
    }
    float4 o0 = {s[0] * 0.0625f, s[1] * 0.0625f, s[2] * 0.0625f, s[3] * 0.0625f};
    float4 o1 = {s[4] * 0.0625f, s[5] * 0.0625f, s[6] * 0.0625f, s[7] * 0.0625f};
    *(float4*)(out + (long)bt * 64 + d0) = o0;
    *(float4*)(out + (long)bt * 64 + d0 + 4) = o1;
}

// ---------------- reduce att_score partials over batch ----------------
__global__ void k_att_reduce(const float* __restrict__ part, float* __restrict__ out,
                             int n, int nb, long stride) {
    int i = blockIdx.x * blockDim.x + threadIdx.x;
    if (i >= n) return;
    float s = 0.f;
    for (int b = 0; b < nb; ++b) s += part[(long)b * stride + i];
    out[i] = s * 0.002707606174062286f;  // ln(2)/256 compensates log2e folded into q
}

// ---------------- V transpose + size pre-scale ----------------
__global__ __launch_bounds__(256) void k_vtrans(const short* __restrict__ v, short* __restrict__ vt,
                                                const float* __restrict__ szp,
                                                int B, int T, int H, int TP, int SP) {
    int b = blockIdx.z, h = blockIdx.y, t0 = blockIdx.x * 64;
    __shared__ short Vs[64][68];
    __shared__ float Szs[64];
    int tid = threadIdx.x;
    if (tid < 64) Szs[tid] = szp[b * SP + t0 + tid];
    for (int c = tid; c < 512; c += 256) {
        int r = c >> 3, m = c & 7;
        s16x8 val = {0,0,0,0,0,0,0,0};
        if (t0 + r < T) val = *(const s16x8*)(v + ((long)(b * T + t0 + r)) * (H * 64) + h * 64 + m * 8);
        *(s16x8*)&Vs[r][m * 8] = val;
    }
    __syncthreads();
    for (int c = tid; c < 512; c += 256) {
        int d = c >> 3, mw = c & 7;
        s16x8 o;
        #pragma unroll
        for (int j = 0; j < 8; j++) o[j] = f2b(b2f(Vs[mw * 8 + j][d]) * Szs[mw * 8 + j]);
        *(s16x8*)(vt + ((long)((b * H + h) * 64 + d)) * TP + t0 + mw * 8) = o;
    }
}

// ---------------- flash attention v7: gload_lds K/V staging (swizzled), low-VGPR ----------------
__global__ __launch_bounds__(256) void k_flash(
    const short* __restrict__ Q, const short* __restrict__ Kb, const short* __restrict__ VT,
    const float* __restrict__ szp, short* __restrict__ Ctx,
    int B, int T, int E, int H, int SP, int TP, int NTQ) {
    int nwg = gridDim.x;
    int cpx = nwg >> 3;
    int wg = (blockIdx.x & 7) * cpx + (blockIdx.x >> 3);
    int tq = wg % NTQ, h = (wg / NTQ) % H, b = wg / (NTQ * H);
    int t0 = tq * 64;

    __shared__ short KsL[64 * 64];
    __shared__ short VtL[80 * 64];
    __shared__ short Ps[4][16][68];
    int tid = threadIdx.x, wid = tid >> 6, lane = tid & 63;
    int lr = lane & 15, lg = lane >> 4;

    for (int c = tid; c < 15 * 64; c += 256) VtL[65 * 64 + c] = 0;

    s16x8 aqf[2];
    {
        int t = t0 + wid * 16 + lr; t = t < T ? t : T - 1;
        #pragma unroll
        for (int ks = 0; ks < 2; ++ks)
            aqf[ks] = *(const s16x8*)(Q + ((long)b * T + t) * E + h * 64 + ks * 32 + lg * 8);
    }

    const short* kb  = Kb + (long)b * T * E + h * 64;
    const short* vtb = VT + ((long)(b * H + h)) * 64 * TP;

    int ch0 = tid, ch1 = tid + 256;
    int kr0 = ch0 >> 3, kc0 = ((ch0 & 7) * 16) ^ ((kr0 & 7) << 4);
    int kr1 = ch1 >> 3, kc1 = ((ch1 & 7) * 16) ^ ((kr1 & 7) << 4);

    float szreg = (tid < 64) ? szp[b * SP + tid] : 0.f;

    float mreg[4];
    f32x4 o[5];
    #pragma unroll
    for (int q = 0; q < 4; q++) mreg[q] = -INFINITY;
    #pragma unroll
    for (int jd = 0; jd < 5; jd++)
        #pragma unroll
        for (int q = 0; q < 4; q++) o[jd][q] = 0.f;

    for (int s0 = 0; s0 < T; s0 += 64) {
        __syncthreads();
        {
            int s = s0 + kr0; s = s < T ? s : T - 1;
            gload16((const char*)(kb + (long)s * E) + kc0, &KsL[ch0 * 8]);
            s = s0 + kr1; s = s < T ? s : T - 1;
            gload16((const char*)(kb + (long)s * E) + kc1, &KsL[ch1 * 8]);
            gload16((const char*)(vtb + (long)kr0 * TP + s0) + kc0, &VtL[ch0 * 8]);
            gload16((const char*)(vtb + (long)kr1 * TP + s0) + kc1, &VtL[ch1 * 8]);
        }
        if (tid < 64) {
            VtL[64 * 64 + tid] = f2b(szreg);
            if (s0 + 64 < T) szreg = szp[b * SP + s0 + 64 + tid];
        }
        asm volatile("s_waitcnt vmcnt(0)" ::: "memory");
        __syncthreads();

        f32x4 sf[4];
        #pragma unroll
        for (int j = 0; j < 4; j++)
            #pragma unroll
            for (int q = 0; q < 4; q++) sf[j][q] = 0.f;
        __builtin_amdgcn_s_setprio(1);
        #pragma unroll
        for (int ks = 0; ks < 2; ++ks)
            #pragma unroll
            for (int j = 0; j < 4; j++) {
                int r = j * 16 + lr;
                s16x8 bk = *(const s16x8*)((const char*)KsL + r * 128 +
                           (((ks << 6) + (lg << 4)) ^ ((r & 7) << 4)));
                sf[j] = MFMA16(aqf[ks], bk, sf[j]);
            }
        __builtin_amdgcn_s_setprio(0);

        float tmax[4];
        #pragma unroll
        for (int q = 0; q < 4; q++)
            tmax[q] = fmaxf(fmaxf(sf[0][q], sf[1][q]), fmaxf(sf[2][q], sf[3][q]));
        int ok = 1;
        #pragma unroll
        for (int q = 0; q < 4; q++) ok &= (tmax[q] <= mreg[q] + 11.0f) ? 1 : 0;
        if (!__all(ok)) {
            #pragma unroll
            for (int q = 0; q < 4; q++) {
                #pragma unroll
                for (int msk = 1; msk < 16; msk <<= 1)
                    tmax[q] = fmaxf(tmax[q], __shfl_xor(tmax[q], msk));
                float mn = fmaxf(mreg[q], tmax[q]);
                float al = exp2f(mreg[q] - mn);
                mreg[q] = mn;
                #pragma unroll
                for (int jd = 0; jd < 5; jd++) o[jd][q] *= al;
            }
        }
        #pragma unroll
        for (int j = 0; j < 4; j++)
            #pragma unroll
            for (int q = 0; q < 4; q++)
                Ps[wid][lg * 4 + q][j * 16 + lr] = f2b(exp2f(sf[j][q] - mreg[q]));

        __builtin_amdgcn_s_setprio(1);
        #pragma unroll
        for (int ks = 0; ks < 2; ++ks) {
            s16x8 ap = *(const s16x8*)&Ps[wid][lr][ks * 32 + lg * 8];
            #pragma unroll
            for (int jd = 0; jd < 5; jd++) {
                int r = jd * 16 + lr;
                s16x8 bv = *(const s16x8*)((const char*)VtL + r * 128 +
                           (((ks << 6) + (lg << 4)) ^ ((r & 7) << 4)));
                o[jd] = MFMA16(ap, bv, o[jd]);
            }
        }
        __builtin_amdgcn_s_setprio(0);
    }

    short* cb = Ctx + ((long)b * T + t0) * E + h * 64;
    #pragma unroll
    for (int q = 0; q < 4; q++) {
        float s = __shfl(o[4][q], lane & 48);
        int t = wid * 16 + lg * 4 + q;
        if (t0 + t >= T) continue;
        float inv = 1.f / s;
        #pragma unroll
        for (int jd = 0; jd < 4; jd++)
            cb[(long)t * E + jd * 16 + lr] = f2b(o[jd][q] * inv);
    }
}

extern "C" void kernel_launch(void* const* d_in, const int* in_sizes, int n_in,
                              void* d_out, int out_size, void* d_ws, size_t ws_size,
                              hipStream_t stream) {
    (void)in_sizes; (void)n_in; (void)out_size; (void)ws_size;
    const int B = 16, T = 577, E = 1024, H = 16;
    const int SP = 640, TP = 640;
    const float* hs   = (const float*)d_in[0];
    const float* size = (const float*)d_in[1];
    const float* wq   = (const float*)d_in[2];
    const float* bq   = (const float*)d_in[3];
    const float* wk   = (const float*)d_in[4];
    const float* bk   = (const float*)d_in[5];
    const float* wv   = (const float*)d_in[6];
    const float* bv   = (const float*)d_in[7];
    const float* wo   = (const float*)d_in[8];
    const float* bo   = (const float*)d_in[9];

    float* out_attn = (float*)d_out;                  // B*T*E
    float* out_mk   = out_attn + (long)B * T * E;     // B*T*D
    float* out_as   = out_mk + (long)B * T * 64;      // T*T

    long nBTE = (long)B * T * E;
    long nEE  = (long)E * E;
    char* ws = (char*)d_ws;
    short* hs_b  = (short*)ws; ws += nBTE * 2;
    short* wq_b  = (short*)ws; ws += nEE * 2;   // wq|wk|wv|wo contiguous
    short* wk_b  = (short*)ws; ws += nEE * 2;
    short* wv_b  = (short*)ws; ws += nEE * 2;
    short* wo_b  = (short*)ws; ws += nEE * 2;
    short* q_b   = (short*)ws; ws += nBTE * 2;
    short* k_b   = (short*)ws; ws += nBTE * 2;
    short* v_b   = (short*)ws; ws += nBTE * 2;
    short* ctx_b = (short*)ws; ws += nBTE * 2;
    float* szpad = (float*)ws; ws += (long)B * SP * 4;
    float* att_p = (float*)ws; ws += (long)B * T * T * 4;
    short* vt = (short*)att_p;   // aliases att_p, written after reduce consumed it

    k_f32_to_bf16<<<2048, 256, 0, stream>>>(hs, hs_b, nBTE);
    {
        dim3 gw((nEE / 4 + 255) / 256, 4);
        k_wconv4<<<gw, 256, 0, stream>>>(wq, wk, wv, wo, wq_b, nEE);
    }
    k_sizepad<<<(B * SP + 255) / 256, 256, 0, stream>>>(size, szpad, B, T, SP);

    int M = B * T;  // 9232
    {
        int Mtiles = (M + 127) / 128, Ntiles = 3072 / 128;   // 73 x 24 = 1752 blocks
        k_gemm8w<true><<<Mtiles * Ntiles, 512, 0, stream>>>(
            hs_b, wq_b, bq, bk, bv, q_b, k_b, v_b, nullptr, M, 3072, E, Ntiles,
            0.18033688011112042f);  // 0.125 * log2(e)
    }

    // att partials: 8-wave core, flattened grid 16*5*5 = 400 blocks (single resident round)
    {
        int Ntiles = (T + 127) / 128;                        // 5
        int natt = B * Ntiles * Ntiles;                      // 400 (%8==0)
        k_att8w<<<natt, 512, 0, stream>>>(q_b, k_b, att_p, T, E, Ntiles);
    }
    k_att_reduce<<<((T * T) + 255) / 256, 256, 0, stream>>>(att_p, out_as, T * T, B, (long)T * T);

    dim3 g_vt((T + 63) / 64, H, B);
    k_vtrans<<<g_vt, dim3(256), 0, stream>>>(v_b, vt, szpad, B, T, H, TP, SP);

    k_mean_keys8<<<((B * T * 8) + 255) / 256, 256, 0, stream>>>(k_b, out_mk, B * T);

    const int NTQ = (T + 63) / 64;   // 10 -> 2560 blocks (%8==0)
    int nfl = NTQ * H * B;
    k_flash<<<nfl, dim3(256), 0, stream>>>(q_b, k_b, vt, szpad, ctx_b, B, T, E, H, SP, TP, NTQ);

    // output projection: 8-wave core, 584 blocks (single resident round)
    {
        int Mtiles = (M + 127) / 128, Ntiles = 1024 / 128;   // 73 x 8 = 584 blocks
        k_proj8w<<<Mtiles * Ntiles, 512, 0, stream>>>(
            ctx_b, wo_b, bo, out_attn, M, 1024, E, Ntiles);
    }
}